// Round 11
// baseline (433.306 us; speedup 1.0000x reference)
//
#include <hip/hip_runtime.h>
#include <math.h>

#define N1T 65536
#define N2T 16384
#define BSZ 8
#define N1B 8192   // points per batch in xyz1
#define N2B 2048   // points per batch in xyz2
#define C1 256
#define C2 512
#define K1 768     // C1 + C2
#define HID 256
#define BN_EPS 1e-5f

typedef short bf16x8 __attribute__((ext_vector_type(8)));
typedef float f32x4 __attribute__((ext_vector_type(4)));

// Exact single-rounded f32 ops via ISA — immune to -ffast-math / contraction.
__device__ __forceinline__ float mul_rn(float a, float b) {
    float r; asm("v_mul_f32 %0, %1, %2" : "=v"(r) : "v"(a), "v"(b)); return r;
}
__device__ __forceinline__ float add_rn(float a, float b) {
    float r; asm("v_add_f32 %0, %1, %2" : "=v"(r) : "v"(a), "v"(b)); return r;
}
__device__ __forceinline__ float sub_rn(float a, float b) {
    float r; asm("v_sub_f32 %0, %1, %2" : "=v"(r) : "v"(a), "v"(b)); return r;
}
__device__ __forceinline__ float fma_rn(float a, float b, float c) {
    float r; asm("v_fma_f32 %0, %1, %2, %3" : "=v"(r) : "v"(a), "v"(b), "v"(c)); return r;
}
// f32 -> bf16 round-to-nearest-even
__device__ __forceinline__ short f2bf(float f) {
    unsigned u = __builtin_bit_cast(unsigned, f);
    u += 0x7fffu + ((u >> 16) & 1u);
    return (short)(u >> 16);
}

// ---------------------------------------------------------------- KNN-3
// FROZEN arithmetic (r9): d2 = (qq - 2*dot) + kk, nofma qq/kk, fma-asc dot.
// r11 restructure: refs packed float4(x,y,z,kk) -> 1 broadcast ds_read_b128;
// 4 independent j-streams (ILP, hides LDS+VALU latency at 1 wave/SIMD);
// lexicographic (d, idx) merge == sequential strict-< scan (stable tiebreak).
__global__ __launch_bounds__(256) void knn_kernel(
    const float* __restrict__ xyz1, const float* __restrict__ xyz2,
    int* __restrict__ idx_out, float* __restrict__ w_out)
{
    __shared__ float4 sref[N2B];
    const int tid = threadIdx.x;
    const int qbase = blockIdx.x * 256;      // 256 blocks x 256 queries
    const int batch = qbase / N1B;           // block never straddles batches
    const float* k2 = xyz2 + (size_t)batch * N2B * 3;
    for (int p = tid; p < N2B; p += 256) {
        float x = k2[3 * p], y = k2[3 * p + 1], z = k2[3 * p + 2];
        float kk = add_rn(add_rn(mul_rn(x, x), mul_rn(y, y)), mul_rn(z, z));
        sref[p] = make_float4(x, y, z, kk);
    }
    __syncthreads();

    const int q = qbase + tid;
    const float qx = xyz1[q * 3 + 0], qy = xyz1[q * 3 + 1], qz = xyz1[q * 3 + 2];
    const float qq = add_rn(add_rn(mul_rn(qx, qx), mul_rn(qy, qy)), mul_rn(qz, qz));

    // 4 independent streams: s covers [s*512, (s+1)*512)
    float sb0[4], sb1[4], sb2[4];
    int   si0[4], si1[4], si2[4];
#pragma unroll
    for (int s = 0; s < 4; ++s) {
        sb0[s] = sb1[s] = sb2[s] = 1e30f;
        si0[s] = si1[s] = si2[s] = 0x7fffffff;
    }
    for (int jj = 0; jj < 512; ++jj) {
        float4 r[4];
        r[0] = sref[jj];
        r[1] = sref[jj + 512];
        r[2] = sref[jj + 1024];
        r[3] = sref[jj + 1536];
        float dv[4];
#pragma unroll
        for (int s = 0; s < 4; ++s) {
            float p0 = mul_rn(qx, r[s].x);
            float dt = fma_rn(qz, r[s].z, fma_rn(qy, r[s].y, p0));
            dv[s] = add_rn(sub_rn(qq, add_rn(dt, dt)), r[s].w);
        }
#pragma unroll
        for (int s = 0; s < 4; ++s) {
            const float d = dv[s];
            const int j = jj + s * 512;
            if (d < sb2[s]) {
                if (d < sb1[s]) {
                    sb2[s] = sb1[s]; si2[s] = si1[s];
                    if (d < sb0[s]) { sb1[s] = sb0[s]; si1[s] = si0[s]; sb0[s] = d; si0[s] = j; }
                    else            { sb1[s] = d; si1[s] = j; }
                } else { sb2[s] = d; si2[s] = j; }
            }
        }
    }
    // merge 12 candidates lexicographically by (d, idx)
    float bd0 = 1e30f, bd1 = 1e30f, bd2 = 1e30f;
    int   bi0 = 0x7fffffff, bi1 = 0x7fffffff, bi2 = 0x7fffffff;
#pragma unroll
    for (int s = 0; s < 4; ++s) {
        float cd[3] = {sb0[s], sb1[s], sb2[s]};
        int   ci[3] = {si0[s], si1[s], si2[s]};
#pragma unroll
        for (int t = 0; t < 3; ++t) {
            const float d = cd[t]; const int ji = ci[t];
            if ((d < bd2) || (d == bd2 && ji < bi2)) {
                if ((d < bd1) || (d == bd1 && ji < bi1)) {
                    bd2 = bd1; bi2 = bi1;
                    if ((d < bd0) || (d == bd0 && ji < bi0)) {
                        bd1 = bd0; bi1 = bi0; bd0 = d; bi0 = ji;
                    } else { bd1 = d; bi1 = ji; }
                } else { bd2 = d; bi2 = ji; }
            }
        }
    }
    float d0s = __fsqrt_rn(fmaxf(bd0, 0.0f));
    float d1s = __fsqrt_rn(fmaxf(bd1, 0.0f));
    float d2s = __fsqrt_rn(fmaxf(bd2, 0.0f));
    float r0 = __fdiv_rn(1.0f, add_rn(d0s, 1e-8f));
    float r1 = __fdiv_rn(1.0f, add_rn(d1s, 1e-8f));
    float r2 = __fdiv_rn(1.0f, add_rn(d2s, 1e-8f));
    float rs = add_rn(add_rn(r0, r1), r2);
    w_out[q * 3 + 0] = __fdiv_rn(r0, rs);
    w_out[q * 3 + 1] = __fdiv_rn(r1, rs);
    w_out[q * 3 + 2] = __fdiv_rn(r2, rs);
    idx_out[q * 3 + 0] = batch * N2B + bi0;
    idx_out[q * 3 + 1] = batch * N2B + bi1;
    idx_out[q * 3 + 2] = batch * N2B + bi2;
}

// ------------------------------------------------- IDW interpolation gather
__global__ __launch_bounds__(128) void interp_kernel(
    const float* __restrict__ points2, const int* __restrict__ idx,
    const float* __restrict__ w, short* __restrict__ interpb)
{
    const int row = blockIdx.x;
    const int c4 = threadIdx.x;          // 4 cols per thread, 128*4 = 512
    const int j0 = idx[row * 3 + 0], j1 = idx[row * 3 + 1], j2 = idx[row * 3 + 2];
    const float w0 = w[row * 3 + 0], w1 = w[row * 3 + 1], w2 = w[row * 3 + 2];
    const float4 a = ((const float4*)(points2 + (size_t)j0 * C2))[c4];
    const float4 b = ((const float4*)(points2 + (size_t)j1 * C2))[c4];
    const float4 c = ((const float4*)(points2 + (size_t)j2 * C2))[c4];
    float ox = add_rn(add_rn(mul_rn(a.x, w0), mul_rn(b.x, w1)), mul_rn(c.x, w2));
    float oy = add_rn(add_rn(mul_rn(a.y, w0), mul_rn(b.y, w1)), mul_rn(c.y, w2));
    float oz = add_rn(add_rn(mul_rn(a.z, w0), mul_rn(b.z, w1)), mul_rn(c.z, w2));
    float ow = add_rn(add_rn(mul_rn(a.w, w0), mul_rn(b.w, w1)), mul_rn(c.w, w2));
    short4 o4; o4.x = f2bf(ox); o4.y = f2bf(oy); o4.z = f2bf(oz); o4.w = f2bf(ow);
    *(short4*)(interpb + (size_t)row * C2 + c4 * 4) = o4;
}

// ------------------------------------------------------ prep: casts/transposes
__global__ __launch_bounds__(256) void cast_p1_kernel(
    const float* __restrict__ p1, short* __restrict__ p1b)
{
    const size_t i = ((size_t)blockIdx.x * 256 + threadIdx.x) * 8;
    float4 u0 = *(const float4*)(p1 + i);
    float4 u1 = *(const float4*)(p1 + i + 4);
    bf16x8 v;
    v[0] = f2bf(u0.x); v[1] = f2bf(u0.y); v[2] = f2bf(u0.z); v[3] = f2bf(u0.w);
    v[4] = f2bf(u1.x); v[5] = f2bf(u1.y); v[6] = f2bf(u1.z); v[7] = f2bf(u1.w);
    *(bf16x8*)(p1b + i) = v;
}

// W[K][N] f32 -> WT[N][K] bf16
__global__ __launch_bounds__(256) void transpose_w_kernel(
    const float* __restrict__ Win, short* __restrict__ WT, int K, int N)
{
    const int e = blockIdx.x * 256 + threadIdx.x;
    const int k = e / N, n = e % N;
    WT[(size_t)n * K + k] = f2bf(Win[e]);
}

// --------------------------------------------- bf16 MFMA GEMMs (128x128 tile)
#define LDP 40

// y1 = concat(points1, interp) @ W1 + b1   (A bf16, B = W1^T bf16, acc f32)
__global__ __launch_bounds__(256) void gemm1m_kernel(
    const short* __restrict__ p1b, const short* __restrict__ interpb,
    const short* __restrict__ w1t, const float* __restrict__ bias,
    float* __restrict__ y1)
{
    __shared__ short As[128][LDP];
    __shared__ short Bs[128][LDP];
    const int tid = threadIdx.x;
    const int lane = tid & 63, wv = tid >> 6;
    const int wr = wv >> 1, wc = wv & 1;
    const int l16 = lane & 15, kh = (lane >> 4) * 8;
    const int row0 = blockIdx.y * 128, col0 = blockIdx.x * 128;
    f32x4 acc[4][4];
#pragma unroll
    for (int m = 0; m < 4; ++m)
#pragma unroll
        for (int n = 0; n < 4; ++n) acc[m][n] = (f32x4){0.f, 0.f, 0.f, 0.f};

    const int c0 = tid * 2;                 // 2 chunks of 8 bf16 per thread
    const int r0c = c0 >> 2, kc0 = (c0 & 3) * 8;
    const int r1c = (c0 + 1) >> 2, kc1 = ((c0 + 1) & 3) * 8;

    for (int kt = 0; kt < K1 / 32; ++kt) {
        const int k0 = kt * 32;
        bf16x8 va, vb, wa, wb;
        if (k0 < C1) {
            va = *(const bf16x8*)(p1b + (size_t)(row0 + r0c) * C1 + k0 + kc0);
            vb = *(const bf16x8*)(p1b + (size_t)(row0 + r1c) * C1 + k0 + kc1);
        } else {
            va = *(const bf16x8*)(interpb + (size_t)(row0 + r0c) * C2 + (k0 - C1) + kc0);
            vb = *(const bf16x8*)(interpb + (size_t)(row0 + r1c) * C2 + (k0 - C1) + kc1);
        }
        wa = *(const bf16x8*)(w1t + (size_t)(col0 + r0c) * K1 + k0 + kc0);
        wb = *(const bf16x8*)(w1t + (size_t)(col0 + r1c) * K1 + k0 + kc1);
        __syncthreads();
        *(bf16x8*)(&As[r0c][kc0]) = va;
        *(bf16x8*)(&As[r1c][kc1]) = vb;
        *(bf16x8*)(&Bs[r0c][kc0]) = wa;
        *(bf16x8*)(&Bs[r1c][kc1]) = wb;
        __syncthreads();

        bf16x8 af[4], bf[4];
#pragma unroll
        for (int m = 0; m < 4; ++m)
            af[m] = *(const bf16x8*)(&As[wr * 64 + m * 16 + l16][kh]);
#pragma unroll
        for (int n = 0; n < 4; ++n)
            bf[n] = *(const bf16x8*)(&Bs[wc * 64 + n * 16 + l16][kh]);
#pragma unroll
        for (int m = 0; m < 4; ++m)
#pragma unroll
            for (int n = 0; n < 4; ++n)
                acc[m][n] = __builtin_amdgcn_mfma_f32_16x16x32_bf16(
                    af[m], bf[n], acc[m][n], 0, 0, 0);
    }
#pragma unroll
    for (int n = 0; n < 4; ++n) {
        const int col = col0 + wc * 64 + n * 16 + l16;
        const float bv = bias[col];
#pragma unroll
        for (int m = 0; m < 4; ++m) {
            const int rowb = row0 + wr * 64 + m * 16 + (lane >> 4) * 4;
#pragma unroll
            for (int j = 0; j < 4; ++j)
                y1[(size_t)(rowb + j) * HID + col] = acc[m][n][j] + bv;
        }
    }
}

// y2 = relu(bn(y1)) @ W2 + b2   (BN+ReLU+bf16-cast fused into A staging)
__global__ __launch_bounds__(256) void gemm2m_kernel(
    const float* __restrict__ y1, const float* __restrict__ scale,
    const float* __restrict__ shift, const short* __restrict__ w2t,
    const float* __restrict__ bias, float* __restrict__ y2)
{
    __shared__ short As[128][LDP];
    __shared__ short Bs[128][LDP];
    const int tid = threadIdx.x;
    const int lane = tid & 63, wv = tid >> 6;
    const int wr = wv >> 1, wc = wv & 1;
    const int l16 = lane & 15, kh = (lane >> 4) * 8;
    const int row0 = blockIdx.y * 128, col0 = blockIdx.x * 128;
    f32x4 acc[4][4];
#pragma unroll
    for (int m = 0; m < 4; ++m)
#pragma unroll
        for (int n = 0; n < 4; ++n) acc[m][n] = (f32x4){0.f, 0.f, 0.f, 0.f};

    const int c0 = tid * 2;
    const int r0c = c0 >> 2, kc0 = (c0 & 3) * 8;
    const int r1c = (c0 + 1) >> 2, kc1 = ((c0 + 1) & 3) * 8;

    for (int kt = 0; kt < HID / 32; ++kt) {
        const int k0 = kt * 32;
        float4 u0 = *(const float4*)(y1 + (size_t)(row0 + r0c) * HID + k0 + kc0);
        float4 u1 = *(const float4*)(y1 + (size_t)(row0 + r0c) * HID + k0 + kc0 + 4);
        float4 s0 = *(const float4*)(scale + k0 + kc0);
        float4 s1 = *(const float4*)(scale + k0 + kc0 + 4);
        float4 h0 = *(const float4*)(shift + k0 + kc0);
        float4 h1 = *(const float4*)(shift + k0 + kc0 + 4);
        bf16x8 va;
        va[0] = f2bf(fmaxf(fmaf(u0.x, s0.x, h0.x), 0.f));
        va[1] = f2bf(fmaxf(fmaf(u0.y, s0.y, h0.y), 0.f));
        va[2] = f2bf(fmaxf(fmaf(u0.z, s0.z, h0.z), 0.f));
        va[3] = f2bf(fmaxf(fmaf(u0.w, s0.w, h0.w), 0.f));
        va[4] = f2bf(fmaxf(fmaf(u1.x, s1.x, h1.x), 0.f));
        va[5] = f2bf(fmaxf(fmaf(u1.y, s1.y, h1.y), 0.f));
        va[6] = f2bf(fmaxf(fmaf(u1.z, s1.z, h1.z), 0.f));
        va[7] = f2bf(fmaxf(fmaf(u1.w, s1.w, h1.w), 0.f));
        float4 u2 = *(const float4*)(y1 + (size_t)(row0 + r1c) * HID + k0 + kc1);
        float4 u3 = *(const float4*)(y1 + (size_t)(row0 + r1c) * HID + k0 + kc1 + 4);
        float4 s2 = *(const float4*)(scale + k0 + kc1);
        float4 s3 = *(const float4*)(scale + k0 + kc1 + 4);
        float4 h2 = *(const float4*)(shift + k0 + kc1);
        float4 h3 = *(const float4*)(shift + k0 + kc1 + 4);
        bf16x8 vb;
        vb[0] = f2bf(fmaxf(fmaf(u2.x, s2.x, h2.x), 0.f));
        vb[1] = f2bf(fmaxf(fmaf(u2.y, s2.y, h2.y), 0.f));
        vb[2] = f2bf(fmaxf(fmaf(u2.z, s2.z, h2.z), 0.f));
        vb[3] = f2bf(fmaxf(fmaf(u2.w, s2.w, h2.w), 0.f));
        vb[4] = f2bf(fmaxf(fmaf(u3.x, s3.x, h3.x), 0.f));
        vb[5] = f2bf(fmaxf(fmaf(u3.y, s3.y, h3.y), 0.f));
        vb[6] = f2bf(fmaxf(fmaf(u3.z, s3.z, h3.z), 0.f));
        vb[7] = f2bf(fmaxf(fmaf(u3.w, s3.w, h3.w), 0.f));
        bf16x8 wa = *(const bf16x8*)(w2t + (size_t)(col0 + r0c) * HID + k0 + kc0);
        bf16x8 wb = *(const bf16x8*)(w2t + (size_t)(col0 + r1c) * HID + k0 + kc1);
        __syncthreads();
        *(bf16x8*)(&As[r0c][kc0]) = va;
        *(bf16x8*)(&As[r1c][kc1]) = vb;
        *(bf16x8*)(&Bs[r0c][kc0]) = wa;
        *(bf16x8*)(&Bs[r1c][kc1]) = wb;
        __syncthreads();

        bf16x8 af[4], bf[4];
#pragma unroll
        for (int m = 0; m < 4; ++m)
            af[m] = *(const bf16x8*)(&As[wr * 64 + m * 16 + l16][kh]);
#pragma unroll
        for (int n = 0; n < 4; ++n)
            bf[n] = *(const bf16x8*)(&Bs[wc * 64 + n * 16 + l16][kh]);
#pragma unroll
        for (int m = 0; m < 4; ++m)
#pragma unroll
            for (int n = 0; n < 4; ++n)
                acc[m][n] = __builtin_amdgcn_mfma_f32_16x16x32_bf16(
                    af[m], bf[n], acc[m][n], 0, 0, 0);
    }
#pragma unroll
    for (int n = 0; n < 4; ++n) {
        const int col = col0 + wc * 64 + n * 16 + l16;
        const float bv = bias[col];
#pragma unroll
        for (int m = 0; m < 4; ++m) {
            const int rowb = row0 + wr * 64 + m * 16 + (lane >> 4) * 4;
#pragma unroll
            for (int j = 0; j < 4; ++j)
                y2[(size_t)(rowb + j) * HID + col] = acc[m][n][j] + bv;
        }
    }
}

// ----------------------------------------------------- BN stats (2-stage)
__global__ __launch_bounds__(256) void bn_stats_kernel(
    const float* __restrict__ y, float* __restrict__ psum, float* __restrict__ psq)
{
    const int c = threadIdx.x;
    const size_t r0 = (size_t)blockIdx.x * 256;
    float s = 0.0f, q = 0.0f;
    for (int r = 0; r < 256; ++r) {
        float v = y[(r0 + r) * HID + c];
        s += v;
        q = fmaf(v, v, q);
    }
    psum[blockIdx.x * 256 + c] = s;
    psq[blockIdx.x * 256 + c] = q;
}

__global__ __launch_bounds__(256) void bn_finalize_kernel(
    const float* __restrict__ psum, const float* __restrict__ psq,
    const float* __restrict__ g, const float* __restrict__ be,
    float* __restrict__ scale, float* __restrict__ shift)
{
    const int c = threadIdx.x;
    float s = 0.0f, q = 0.0f;
    for (int b = 0; b < 256; ++b) { s += psum[b * 256 + c]; q += psq[b * 256 + c]; }
    const float inv_n = 1.0f / (float)N1T;
    const float mu = s * inv_n;
    const float var = fmaxf(q * inv_n - mu * mu, 0.0f);
    const float sc = g[c] * rsqrtf(var + BN_EPS);
    scale[c] = sc;
    shift[c] = be[c] - mu * sc;
}

// --------------------------------------------------------- final BN+ReLU
__global__ __launch_bounds__(256) void bn_apply_kernel(
    const float* __restrict__ y, const float* __restrict__ scale,
    const float* __restrict__ shift, float* __restrict__ out)
{
    const size_t i = (size_t)blockIdx.x * 256 + threadIdx.x;  // float4 index
    const int c4 = (int)(i & 63) * 4;
    float4 v = ((const float4*)y)[i];
    const float4 sc = *(const float4*)(scale + c4);
    const float4 sh = *(const float4*)(shift + c4);
    float4 o;
    o.x = fmaxf(fmaf(v.x, sc.x, sh.x), 0.0f);
    o.y = fmaxf(fmaf(v.y, sc.y, sh.y), 0.0f);
    o.z = fmaxf(fmaf(v.z, sc.z, sh.z), 0.0f);
    o.w = fmaxf(fmaf(v.w, sc.w, sh.w), 0.0f);
    ((float4*)out)[i] = o;
}

// -------------------------------------------------------------- launcher
extern "C" void kernel_launch(void* const* d_in, const int* in_sizes, int n_in,
                              void* d_out, int out_size, void* d_ws, size_t ws_size,
                              hipStream_t stream)
{
    const float* xyz1    = (const float*)d_in[0];
    const float* points1 = (const float*)d_in[1];
    const float* xyz2    = (const float*)d_in[2];
    const float* points2 = (const float*)d_in[3];
    const float* W1  = (const float*)d_in[6];
    const float* b1  = (const float*)d_in[7];
    const float* g1  = (const float*)d_in[8];
    const float* be1 = (const float*)d_in[9];
    const float* W2  = (const float*)d_in[10];
    const float* b2  = (const float*)d_in[11];
    const float* g2  = (const float*)d_in[12];
    const float* be2 = (const float*)d_in[13];
    float* out = (float*)d_out;

    char* ws = (char*)d_ws;
    short* interpb = (short*)ws;                   // bf16 [N1,512]; y2 f32 later
    float* y1      = (float*)(ws + 67108864);
    short* p1b     = (short*)(ws + 134217728);
    size_t off     = 134217728 + 33554432;
    short* w1t     = (short*)(ws + off); off += (size_t)K1 * HID * 2;
    short* w2t     = (short*)(ws + off); off += (size_t)HID * HID * 2;
    int*   idx     = (int*)(ws + off);   off += (size_t)N1T * 3 * 4;
    float* w       = (float*)(ws + off); off += (size_t)N1T * 3 * 4;
    float* psum    = (float*)(ws + off); off += 256 * 256 * 4;
    float* psq     = (float*)(ws + off); off += 256 * 256 * 4;
    float* scale1  = (float*)(ws + off); off += 256 * 4;
    float* shift1  = (float*)(ws + off); off += 256 * 4;
    float* scale2  = (float*)(ws + off); off += 256 * 4;
    float* shift2  = (float*)(ws + off); off += 256 * 4;
    float* y2 = (float*)interpb;  // reuse: interp dead after gemm1

    cast_p1_kernel<<<N1T * C1 / 8 / 256, 256, 0, stream>>>(points1, p1b);
    transpose_w_kernel<<<K1 * HID / 256, 256, 0, stream>>>(W1, w1t, K1, HID);
    transpose_w_kernel<<<HID * HID / 256, 256, 0, stream>>>(W2, w2t, HID, HID);
    knn_kernel<<<256, 256, 0, stream>>>(xyz1, xyz2, idx, w);
    interp_kernel<<<N1T, 128, 0, stream>>>(points2, idx, w, interpb);
    gemm1m_kernel<<<dim3(HID / 128, N1T / 128), 256, 0, stream>>>(
        p1b, interpb, w1t, b1, y1);
    bn_stats_kernel<<<256, 256, 0, stream>>>(y1, psum, psq);
    bn_finalize_kernel<<<1, 256, 0, stream>>>(psum, psq, g1, be1, scale1, shift1);
    gemm2m_kernel<<<dim3(HID / 128, N1T / 128), 256, 0, stream>>>(
        y1, scale1, shift1, w2t, b2, y2);
    bn_stats_kernel<<<256, 256, 0, stream>>>(y2, psum, psq);
    bn_finalize_kernel<<<1, 256, 0, stream>>>(psum, psq, g2, be2, scale2, shift2);
    bn_apply_kernel<<<(N1T * HID / 4) / 256, 256, 0, stream>>>(y2, scale2, shift2, out);
}

// Round 12
// 295.737 us; speedup vs baseline: 1.4652x; 1.4652x over previous
//
#include <hip/hip_runtime.h>
#include <math.h>

#define N1T 65536
#define N2T 16384
#define BSZ 8
#define N1B 8192   // points per batch in xyz1
#define N2B 2048   // points per batch in xyz2
#define C1 256
#define C2 512
#define K1 768     // C1 + C2
#define HID 256
#define BN_EPS 1e-5f

typedef short bf16x8 __attribute__((ext_vector_type(8)));
typedef float f32x4 __attribute__((ext_vector_type(4)));

// Exact single-rounded f32 ops via ISA — immune to -ffast-math / contraction.
__device__ __forceinline__ float mul_rn(float a, float b) {
    float r; asm("v_mul_f32 %0, %1, %2" : "=v"(r) : "v"(a), "v"(b)); return r;
}
__device__ __forceinline__ float add_rn(float a, float b) {
    float r; asm("v_add_f32 %0, %1, %2" : "=v"(r) : "v"(a), "v"(b)); return r;
}
__device__ __forceinline__ float sub_rn(float a, float b) {
    float r; asm("v_sub_f32 %0, %1, %2" : "=v"(r) : "v"(a), "v"(b)); return r;
}
__device__ __forceinline__ float fma_rn(float a, float b, float c) {
    float r; asm("v_fma_f32 %0, %1, %2, %3" : "=v"(r) : "v"(a), "v"(b), "v"(c)); return r;
}
// f32 -> bf16 round-to-nearest-even
__device__ __forceinline__ short f2bf(float f) {
    unsigned u = __builtin_bit_cast(unsigned, f);
    u += 0x7fffu + ((u >> 16) & 1u);
    return (short)(u >> 16);
}

// ---------------------------------------------------------------- KNN-3
// FROZEN arithmetic (r9): d2 = (qq - 2*dot) + kk, nofma qq/kk, fma-asc dot.
// r12 restructure: 4 lanes cooperate per query (each scans a disjoint 512-ref
// interval, 2 ILP streams of 256) -> 64 queries/block, grid 1024 = 4 blocks/CU
// (was 1): TLP 1->4 waves/SIMD. Cross-lane merge via shfl_xor with the
// lexicographic (d, idx) insert validated in r11 (== sequential strict-<).
__global__ __launch_bounds__(256) void knn_kernel(
    const float* __restrict__ xyz1, const float* __restrict__ xyz2,
    int* __restrict__ idx_out, float* __restrict__ w_out)
{
    __shared__ float4 sref[N2B];
    const int tid = threadIdx.x;
    const int qbase = blockIdx.x * 64;       // 1024 blocks x 64 queries
    const int batch = qbase / N1B;           // 128 blocks per batch: no straddle
    const float* k2 = xyz2 + (size_t)batch * N2B * 3;
    for (int p = tid; p < N2B; p += 256) {
        float x = k2[3 * p], y = k2[3 * p + 1], z = k2[3 * p + 2];
        float kk = add_rn(add_rn(mul_rn(x, x), mul_rn(y, y)), mul_rn(z, z));
        sref[p] = make_float4(x, y, z, kk);
    }
    __syncthreads();

    const int q = qbase + (tid >> 2);
    const int sub = tid & 3;                 // 4 lanes per query, same wave
    const float qx = xyz1[q * 3 + 0], qy = xyz1[q * 3 + 1], qz = xyz1[q * 3 + 2];
    const float qq = add_rn(add_rn(mul_rn(qx, qx), mul_rn(qy, qy)), mul_rn(qz, qz));

    // two ILP streams of 256 within this lane's interval [sub*512, sub*512+512)
    const int base = sub * 512;
    float a0 = 1e30f, a1 = 1e30f, a2 = 1e30f;   // stream A top-3
    int   ai0 = 0x7fffffff, ai1 = 0x7fffffff, ai2 = 0x7fffffff;
    float c0 = 1e30f, c1 = 1e30f, c2 = 1e30f;   // stream B top-3
    int   ci0 = 0x7fffffff, ci1 = 0x7fffffff, ci2 = 0x7fffffff;
    for (int jj = 0; jj < 256; ++jj) {
        float4 rA = sref[base + jj];
        float4 rB = sref[base + 256 + jj];
        float pA = mul_rn(qx, rA.x);
        float tA = fma_rn(qz, rA.z, fma_rn(qy, rA.y, pA));
        float dA = add_rn(sub_rn(qq, add_rn(tA, tA)), rA.w);
        float pB = mul_rn(qx, rB.x);
        float tB = fma_rn(qz, rB.z, fma_rn(qy, rB.y, pB));
        float dB = add_rn(sub_rn(qq, add_rn(tB, tB)), rB.w);
        if (dA < a2) {
            if (dA < a1) {
                a2 = a1; ai2 = ai1;
                if (dA < a0) { a1 = a0; ai1 = ai0; a0 = dA; ai0 = base + jj; }
                else         { a1 = dA; ai1 = base + jj; }
            } else { a2 = dA; ai2 = base + jj; }
        }
        if (dB < c2) {
            if (dB < c1) {
                c2 = c1; ci2 = ci1;
                if (dB < c0) { c1 = c0; ci1 = ci0; c0 = dB; ci0 = base + 256 + jj; }
                else         { c1 = dB; ci1 = base + 256 + jj; }
            } else { c2 = dB; ci2 = base + 256 + jj; }
        }
    }
    // lexicographic (d, idx) insert of candidate into (bd0..2, bi0..2)
    float bd0 = a0, bd1 = a1, bd2 = a2;
    int   bi0 = ai0, bi1 = ai1, bi2 = ai2;
#define LEXINS(d, ji)                                                        \
    if ((d < bd2) || (d == bd2 && ji < bi2)) {                               \
        if ((d < bd1) || (d == bd1 && ji < bi1)) {                           \
            bd2 = bd1; bi2 = bi1;                                            \
            if ((d < bd0) || (d == bd0 && ji < bi0)) {                       \
                bd1 = bd0; bi1 = bi0; bd0 = d; bi0 = ji;                     \
            } else { bd1 = d; bi1 = ji; }                                    \
        } else { bd2 = d; bi2 = ji; }                                        \
    }
    LEXINS(c0, ci0) LEXINS(c1, ci1) LEXINS(c2, ci2)
    // cross-lane merge: partner lanes sub^1 then sub^2 (same wave)
#pragma unroll
    for (int mask = 1; mask <= 2; mask <<= 1) {
        float pd0 = __shfl_xor(bd0, mask, 64);
        float pd1 = __shfl_xor(bd1, mask, 64);
        float pd2 = __shfl_xor(bd2, mask, 64);
        int   pi0 = __shfl_xor(bi0, mask, 64);
        int   pi1 = __shfl_xor(bi1, mask, 64);
        int   pi2 = __shfl_xor(bi2, mask, 64);
        LEXINS(pd0, pi0) LEXINS(pd1, pi1) LEXINS(pd2, pi2)
    }
#undef LEXINS
    if (sub == 0) {
        float d0s = __fsqrt_rn(fmaxf(bd0, 0.0f));
        float d1s = __fsqrt_rn(fmaxf(bd1, 0.0f));
        float d2s = __fsqrt_rn(fmaxf(bd2, 0.0f));
        float r0 = __fdiv_rn(1.0f, add_rn(d0s, 1e-8f));
        float r1 = __fdiv_rn(1.0f, add_rn(d1s, 1e-8f));
        float r2 = __fdiv_rn(1.0f, add_rn(d2s, 1e-8f));
        float rs = add_rn(add_rn(r0, r1), r2);
        w_out[q * 3 + 0] = __fdiv_rn(r0, rs);
        w_out[q * 3 + 1] = __fdiv_rn(r1, rs);
        w_out[q * 3 + 2] = __fdiv_rn(r2, rs);
        idx_out[q * 3 + 0] = batch * N2B + bi0;
        idx_out[q * 3 + 1] = batch * N2B + bi1;
        idx_out[q * 3 + 2] = batch * N2B + bi2;
    }
}

// ------------------------------------------------- IDW interpolation gather
__global__ __launch_bounds__(128) void interp_kernel(
    const float* __restrict__ points2, const int* __restrict__ idx,
    const float* __restrict__ w, short* __restrict__ interpb)
{
    const int row = blockIdx.x;
    const int c4 = threadIdx.x;          // 4 cols per thread, 128*4 = 512
    const int j0 = idx[row * 3 + 0], j1 = idx[row * 3 + 1], j2 = idx[row * 3 + 2];
    const float w0 = w[row * 3 + 0], w1 = w[row * 3 + 1], w2 = w[row * 3 + 2];
    const float4 a = ((const float4*)(points2 + (size_t)j0 * C2))[c4];
    const float4 b = ((const float4*)(points2 + (size_t)j1 * C2))[c4];
    const float4 c = ((const float4*)(points2 + (size_t)j2 * C2))[c4];
    float ox = add_rn(add_rn(mul_rn(a.x, w0), mul_rn(b.x, w1)), mul_rn(c.x, w2));
    float oy = add_rn(add_rn(mul_rn(a.y, w0), mul_rn(b.y, w1)), mul_rn(c.y, w2));
    float oz = add_rn(add_rn(mul_rn(a.z, w0), mul_rn(b.z, w1)), mul_rn(c.z, w2));
    float ow = add_rn(add_rn(mul_rn(a.w, w0), mul_rn(b.w, w1)), mul_rn(c.w, w2));
    short4 o4; o4.x = f2bf(ox); o4.y = f2bf(oy); o4.z = f2bf(oz); o4.w = f2bf(ow);
    *(short4*)(interpb + (size_t)row * C2 + c4 * 4) = o4;
}

// ------------------------------------------------------ prep: casts/transposes
__global__ __launch_bounds__(256) void cast_p1_kernel(
    const float* __restrict__ p1, short* __restrict__ p1b)
{
    const size_t i = ((size_t)blockIdx.x * 256 + threadIdx.x) * 8;
    float4 u0 = *(const float4*)(p1 + i);
    float4 u1 = *(const float4*)(p1 + i + 4);
    bf16x8 v;
    v[0] = f2bf(u0.x); v[1] = f2bf(u0.y); v[2] = f2bf(u0.z); v[3] = f2bf(u0.w);
    v[4] = f2bf(u1.x); v[5] = f2bf(u1.y); v[6] = f2bf(u1.z); v[7] = f2bf(u1.w);
    *(bf16x8*)(p1b + i) = v;
}

// W[K][N] f32 -> WT[N][K] bf16
__global__ __launch_bounds__(256) void transpose_w_kernel(
    const float* __restrict__ Win, short* __restrict__ WT, int K, int N)
{
    const int e = blockIdx.x * 256 + threadIdx.x;
    const int k = e / N, n = e % N;
    WT[(size_t)n * K + k] = f2bf(Win[e]);
}

// --------------------------------------------- bf16 MFMA GEMMs (128x128 tile)
#define LDP 40

// y1 = concat(points1, interp) @ W1 + b1   (A bf16, B = W1^T bf16, acc f32)
__global__ __launch_bounds__(256) void gemm1m_kernel(
    const short* __restrict__ p1b, const short* __restrict__ interpb,
    const short* __restrict__ w1t, const float* __restrict__ bias,
    float* __restrict__ y1)
{
    __shared__ short As[128][LDP];
    __shared__ short Bs[128][LDP];
    const int tid = threadIdx.x;
    const int lane = tid & 63, wv = tid >> 6;
    const int wr = wv >> 1, wc = wv & 1;
    const int l16 = lane & 15, kh = (lane >> 4) * 8;
    const int row0 = blockIdx.y * 128, col0 = blockIdx.x * 128;
    f32x4 acc[4][4];
#pragma unroll
    for (int m = 0; m < 4; ++m)
#pragma unroll
        for (int n = 0; n < 4; ++n) acc[m][n] = (f32x4){0.f, 0.f, 0.f, 0.f};

    const int c0 = tid * 2;                 // 2 chunks of 8 bf16 per thread
    const int r0c = c0 >> 2, kc0 = (c0 & 3) * 8;
    const int r1c = (c0 + 1) >> 2, kc1 = ((c0 + 1) & 3) * 8;

    for (int kt = 0; kt < K1 / 32; ++kt) {
        const int k0 = kt * 32;
        bf16x8 va, vb, wa, wb;
        if (k0 < C1) {
            va = *(const bf16x8*)(p1b + (size_t)(row0 + r0c) * C1 + k0 + kc0);
            vb = *(const bf16x8*)(p1b + (size_t)(row0 + r1c) * C1 + k0 + kc1);
        } else {
            va = *(const bf16x8*)(interpb + (size_t)(row0 + r0c) * C2 + (k0 - C1) + kc0);
            vb = *(const bf16x8*)(interpb + (size_t)(row0 + r1c) * C2 + (k0 - C1) + kc1);
        }
        wa = *(const bf16x8*)(w1t + (size_t)(col0 + r0c) * K1 + k0 + kc0);
        wb = *(const bf16x8*)(w1t + (size_t)(col0 + r1c) * K1 + k0 + kc1);
        __syncthreads();
        *(bf16x8*)(&As[r0c][kc0]) = va;
        *(bf16x8*)(&As[r1c][kc1]) = vb;
        *(bf16x8*)(&Bs[r0c][kc0]) = wa;
        *(bf16x8*)(&Bs[r1c][kc1]) = wb;
        __syncthreads();

        bf16x8 af[4], bf[4];
#pragma unroll
        for (int m = 0; m < 4; ++m)
            af[m] = *(const bf16x8*)(&As[wr * 64 + m * 16 + l16][kh]);
#pragma unroll
        for (int n = 0; n < 4; ++n)
            bf[n] = *(const bf16x8*)(&Bs[wc * 64 + n * 16 + l16][kh]);
#pragma unroll
        for (int m = 0; m < 4; ++m)
#pragma unroll
            for (int n = 0; n < 4; ++n)
                acc[m][n] = __builtin_amdgcn_mfma_f32_16x16x32_bf16(
                    af[m], bf[n], acc[m][n], 0, 0, 0);
    }
#pragma unroll
    for (int n = 0; n < 4; ++n) {
        const int col = col0 + wc * 64 + n * 16 + l16;
        const float bv = bias[col];
#pragma unroll
        for (int m = 0; m < 4; ++m) {
            const int rowb = row0 + wr * 64 + m * 16 + (lane >> 4) * 4;
#pragma unroll
            for (int j = 0; j < 4; ++j)
                y1[(size_t)(rowb + j) * HID + col] = acc[m][n][j] + bv;
        }
    }
}

// y2 = relu(bn(y1)) @ W2 + b2   (BN+ReLU+bf16-cast fused into A staging)
__global__ __launch_bounds__(256) void gemm2m_kernel(
    const float* __restrict__ y1, const float* __restrict__ scale,
    const float* __restrict__ shift, const short* __restrict__ w2t,
    const float* __restrict__ bias, float* __restrict__ y2)
{
    __shared__ short As[128][LDP];
    __shared__ short Bs[128][LDP];
    const int tid = threadIdx.x;
    const int lane = tid & 63, wv = tid >> 6;
    const int wr = wv >> 1, wc = wv & 1;
    const int l16 = lane & 15, kh = (lane >> 4) * 8;
    const int row0 = blockIdx.y * 128, col0 = blockIdx.x * 128;
    f32x4 acc[4][4];
#pragma unroll
    for (int m = 0; m < 4; ++m)
#pragma unroll
        for (int n = 0; n < 4; ++n) acc[m][n] = (f32x4){0.f, 0.f, 0.f, 0.f};

    const int c0 = tid * 2;
    const int r0c = c0 >> 2, kc0 = (c0 & 3) * 8;
    const int r1c = (c0 + 1) >> 2, kc1 = ((c0 + 1) & 3) * 8;

    for (int kt = 0; kt < HID / 32; ++kt) {
        const int k0 = kt * 32;
        float4 u0 = *(const float4*)(y1 + (size_t)(row0 + r0c) * HID + k0 + kc0);
        float4 u1 = *(const float4*)(y1 + (size_t)(row0 + r0c) * HID + k0 + kc0 + 4);
        float4 s0 = *(const float4*)(scale + k0 + kc0);
        float4 s1 = *(const float4*)(scale + k0 + kc0 + 4);
        float4 h0 = *(const float4*)(shift + k0 + kc0);
        float4 h1 = *(const float4*)(shift + k0 + kc0 + 4);
        bf16x8 va;
        va[0] = f2bf(fmaxf(fmaf(u0.x, s0.x, h0.x), 0.f));
        va[1] = f2bf(fmaxf(fmaf(u0.y, s0.y, h0.y), 0.f));
        va[2] = f2bf(fmaxf(fmaf(u0.z, s0.z, h0.z), 0.f));
        va[3] = f2bf(fmaxf(fmaf(u0.w, s0.w, h0.w), 0.f));
        va[4] = f2bf(fmaxf(fmaf(u1.x, s1.x, h1.x), 0.f));
        va[5] = f2bf(fmaxf(fmaf(u1.y, s1.y, h1.y), 0.f));
        va[6] = f2bf(fmaxf(fmaf(u1.z, s1.z, h1.z), 0.f));
        va[7] = f2bf(fmaxf(fmaf(u1.w, s1.w, h1.w), 0.f));
        float4 u2 = *(const float4*)(y1 + (size_t)(row0 + r1c) * HID + k0 + kc1);
        float4 u3 = *(const float4*)(y1 + (size_t)(row0 + r1c) * HID + k0 + kc1 + 4);
        float4 s2 = *(const float4*)(scale + k0 + kc1);
        float4 s3 = *(const float4*)(scale + k0 + kc1 + 4);
        float4 h2 = *(const float4*)(shift + k0 + kc1);
        float4 h3 = *(const float4*)(shift + k0 + kc1 + 4);
        bf16x8 vb;
        vb[0] = f2bf(fmaxf(fmaf(u2.x, s2.x, h2.x), 0.f));
        vb[1] = f2bf(fmaxf(fmaf(u2.y, s2.y, h2.y), 0.f));
        vb[2] = f2bf(fmaxf(fmaf(u2.z, s2.z, h2.z), 0.f));
        vb[3] = f2bf(fmaxf(fmaf(u2.w, s2.w, h2.w), 0.f));
        vb[4] = f2bf(fmaxf(fmaf(u3.x, s3.x, h3.x), 0.f));
        vb[5] = f2bf(fmaxf(fmaf(u3.y, s3.y, h3.y), 0.f));
        vb[6] = f2bf(fmaxf(fmaf(u3.z, s3.z, h3.z), 0.f));
        vb[7] = f2bf(fmaxf(fmaf(u3.w, s3.w, h3.w), 0.f));
        bf16x8 wa = *(const bf16x8*)(w2t + (size_t)(col0 + r0c) * HID + k0 + kc0);
        bf16x8 wb = *(const bf16x8*)(w2t + (size_t)(col0 + r1c) * HID + k0 + kc1);
        __syncthreads();
        *(bf16x8*)(&As[r0c][kc0]) = va;
        *(bf16x8*)(&As[r1c][kc1]) = vb;
        *(bf16x8*)(&Bs[r0c][kc0]) = wa;
        *(bf16x8*)(&Bs[r1c][kc1]) = wb;
        __syncthreads();

        bf16x8 af[4], bf[4];
#pragma unroll
        for (int m = 0; m < 4; ++m)
            af[m] = *(const bf16x8*)(&As[wr * 64 + m * 16 + l16][kh]);
#pragma unroll
        for (int n = 0; n < 4; ++n)
            bf[n] = *(const bf16x8*)(&Bs[wc * 64 + n * 16 + l16][kh]);
#pragma unroll
        for (int m = 0; m < 4; ++m)
#pragma unroll
            for (int n = 0; n < 4; ++n)
                acc[m][n] = __builtin_amdgcn_mfma_f32_16x16x32_bf16(
                    af[m], bf[n], acc[m][n], 0, 0, 0);
    }
#pragma unroll
    for (int n = 0; n < 4; ++n) {
        const int col = col0 + wc * 64 + n * 16 + l16;
        const float bv = bias[col];
#pragma unroll
        for (int m = 0; m < 4; ++m) {
            const int rowb = row0 + wr * 64 + m * 16 + (lane >> 4) * 4;
#pragma unroll
            for (int j = 0; j < 4; ++j)
                y2[(size_t)(rowb + j) * HID + col] = acc[m][n][j] + bv;
        }
    }
}

// ----------------------------------------------------- BN stats (2-stage)
__global__ __launch_bounds__(256) void bn_stats_kernel(
    const float* __restrict__ y, float* __restrict__ psum, float* __restrict__ psq)
{
    const int c = threadIdx.x;
    const size_t r0 = (size_t)blockIdx.x * 256;
    float s = 0.0f, q = 0.0f;
    for (int r = 0; r < 256; ++r) {
        float v = y[(r0 + r) * HID + c];
        s += v;
        q = fmaf(v, v, q);
    }
    psum[blockIdx.x * 256 + c] = s;
    psq[blockIdx.x * 256 + c] = q;
}

__global__ __launch_bounds__(256) void bn_finalize_kernel(
    const float* __restrict__ psum, const float* __restrict__ psq,
    const float* __restrict__ g, const float* __restrict__ be,
    float* __restrict__ scale, float* __restrict__ shift)
{
    const int c = threadIdx.x;
    float s = 0.0f, q = 0.0f;
    for (int b = 0; b < 256; ++b) { s += psum[b * 256 + c]; q += psq[b * 256 + c]; }
    const float inv_n = 1.0f / (float)N1T;
    const float mu = s * inv_n;
    const float var = fmaxf(q * inv_n - mu * mu, 0.0f);
    const float sc = g[c] * rsqrtf(var + BN_EPS);
    scale[c] = sc;
    shift[c] = be[c] - mu * sc;
}

// --------------------------------------------------------- final BN+ReLU
__global__ __launch_bounds__(256) void bn_apply_kernel(
    const float* __restrict__ y, const float* __restrict__ scale,
    const float* __restrict__ shift, float* __restrict__ out)
{
    const size_t i = (size_t)blockIdx.x * 256 + threadIdx.x;  // float4 index
    const int c4 = (int)(i & 63) * 4;
    float4 v = ((const float4*)y)[i];
    const float4 sc = *(const float4*)(scale + c4);
    const float4 sh = *(const float4*)(shift + c4);
    float4 o;
    o.x = fmaxf(fmaf(v.x, sc.x, sh.x), 0.0f);
    o.y = fmaxf(fmaf(v.y, sc.y, sh.y), 0.0f);
    o.z = fmaxf(fmaf(v.z, sc.z, sh.z), 0.0f);
    o.w = fmaxf(fmaf(v.w, sc.w, sh.w), 0.0f);
    ((float4*)out)[i] = o;
}

// -------------------------------------------------------------- launcher
extern "C" void kernel_launch(void* const* d_in, const int* in_sizes, int n_in,
                              void* d_out, int out_size, void* d_ws, size_t ws_size,
                              hipStream_t stream)
{
    const float* xyz1    = (const float*)d_in[0];
    const float* points1 = (const float*)d_in[1];
    const float* xyz2    = (const float*)d_in[2];
    const float* points2 = (const float*)d_in[3];
    const float* W1  = (const float*)d_in[6];
    const float* b1  = (const float*)d_in[7];
    const float* g1  = (const float*)d_in[8];
    const float* be1 = (const float*)d_in[9];
    const float* W2  = (const float*)d_in[10];
    const float* b2  = (const float*)d_in[11];
    const float* g2  = (const float*)d_in[12];
    const float* be2 = (const float*)d_in[13];
    float* out = (float*)d_out;

    char* ws = (char*)d_ws;
    short* interpb = (short*)ws;                   // bf16 [N1,512]; y2 f32 later
    float* y1      = (float*)(ws + 67108864);
    short* p1b     = (short*)(ws + 134217728);
    size_t off     = 134217728 + 33554432;
    short* w1t     = (short*)(ws + off); off += (size_t)K1 * HID * 2;
    short* w2t     = (short*)(ws + off); off += (size_t)HID * HID * 2;
    int*   idx     = (int*)(ws + off);   off += (size_t)N1T * 3 * 4;
    float* w       = (float*)(ws + off); off += (size_t)N1T * 3 * 4;
    float* psum    = (float*)(ws + off); off += 256 * 256 * 4;
    float* psq     = (float*)(ws + off); off += 256 * 256 * 4;
    float* scale1  = (float*)(ws + off); off += 256 * 4;
    float* shift1  = (float*)(ws + off); off += 256 * 4;
    float* scale2  = (float*)(ws + off); off += 256 * 4;
    float* shift2  = (float*)(ws + off); off += 256 * 4;
    float* y2 = (float*)interpb;  // reuse: interp dead after gemm1

    cast_p1_kernel<<<N1T * C1 / 8 / 256, 256, 0, stream>>>(points1, p1b);
    transpose_w_kernel<<<K1 * HID / 256, 256, 0, stream>>>(W1, w1t, K1, HID);
    transpose_w_kernel<<<HID * HID / 256, 256, 0, stream>>>(W2, w2t, HID, HID);
    knn_kernel<<<1024, 256, 0, stream>>>(xyz1, xyz2, idx, w);
    interp_kernel<<<N1T, 128, 0, stream>>>(points2, idx, w, interpb);
    gemm1m_kernel<<<dim3(HID / 128, N1T / 128), 256, 0, stream>>>(
        p1b, interpb, w1t, b1, y1);
    bn_stats_kernel<<<256, 256, 0, stream>>>(y1, psum, psq);
    bn_finalize_kernel<<<1, 256, 0, stream>>>(psum, psq, g1, be1, scale1, shift1);
    gemm2m_kernel<<<dim3(HID / 128, N1T / 128), 256, 0, stream>>>(
        y1, scale1, shift1, w2t, b2, y2);
    bn_stats_kernel<<<256, 256, 0, stream>>>(y2, psum, psq);
    bn_finalize_kernel<<<1, 256, 0, stream>>>(psum, psq, g2, be2, scale2, shift2);
    bn_apply_kernel<<<(N1T * HID / 4) / 256, 256, 0, stream>>>(y2, scale2, shift2, out);
}

// Round 13
// 291.527 us; speedup vs baseline: 1.4863x; 1.0144x over previous
//
#include <hip/hip_runtime.h>
#include <math.h>

#define N1T 65536
#define N2T 16384
#define BSZ 8
#define N1B 8192   // points per batch in xyz1
#define N2B 2048   // points per batch in xyz2
#define C1 256
#define C2 512
#define K1 768     // C1 + C2
#define HID 256
#define BN_EPS 1e-5f

typedef short bf16x8 __attribute__((ext_vector_type(8)));
typedef float f32x4 __attribute__((ext_vector_type(4)));

// Exact single-rounded f32 ops via ISA — immune to -ffast-math / contraction.
__device__ __forceinline__ float mul_rn(float a, float b) {
    float r; asm("v_mul_f32 %0, %1, %2" : "=v"(r) : "v"(a), "v"(b)); return r;
}
__device__ __forceinline__ float add_rn(float a, float b) {
    float r; asm("v_add_f32 %0, %1, %2" : "=v"(r) : "v"(a), "v"(b)); return r;
}
__device__ __forceinline__ float sub_rn(float a, float b) {
    float r; asm("v_sub_f32 %0, %1, %2" : "=v"(r) : "v"(a), "v"(b)); return r;
}
__device__ __forceinline__ float fma_rn(float a, float b, float c) {
    float r; asm("v_fma_f32 %0, %1, %2, %3" : "=v"(r) : "v"(a), "v"(b), "v"(c)); return r;
}
// f32 -> bf16 round-to-nearest-even
__device__ __forceinline__ short f2bf(float f) {
    unsigned u = __builtin_bit_cast(unsigned, f);
    u += 0x7fffu + ((u >> 16) & 1u);
    return (short)(u >> 16);
}

// ---------------------------------------------------------------- KNN-3
// FROZEN arithmetic (r9). r13: pad sref intervals (stride 513 float4) so the
// 4 sub-lanes' reads land on distinct bank sets (was 4-way conflict, 2.5e7).
__global__ __launch_bounds__(256) void knn_kernel(
    const float* __restrict__ xyz1, const float* __restrict__ xyz2,
    int* __restrict__ idx_out, float* __restrict__ w_out)
{
    __shared__ float4 sref[N2B + 4];         // padded: pos = p + p/512
    const int tid = threadIdx.x;
    const int qbase = blockIdx.x * 64;       // 1024 blocks x 64 queries
    const int batch = qbase / N1B;           // 128 blocks per batch: no straddle
    const float* k2 = xyz2 + (size_t)batch * N2B * 3;
    for (int p = tid; p < N2B; p += 256) {
        float x = k2[3 * p], y = k2[3 * p + 1], z = k2[3 * p + 2];
        float kk = add_rn(add_rn(mul_rn(x, x), mul_rn(y, y)), mul_rn(z, z));
        sref[p + (p >> 9)] = make_float4(x, y, z, kk);
    }
    __syncthreads();

    const int q = qbase + (tid >> 2);
    const int sub = tid & 3;                 // 4 lanes per query, same wave
    const float qx = xyz1[q * 3 + 0], qy = xyz1[q * 3 + 1], qz = xyz1[q * 3 + 2];
    const float qq = add_rn(add_rn(mul_rn(qx, qx), mul_rn(qy, qy)), mul_rn(qz, qz));

    const int base = sub * 513;              // padded LDS base of this interval
    const int gbase = sub * 512;             // global index base
    float a0 = 1e30f, a1 = 1e30f, a2 = 1e30f;
    int   ai0 = 0x7fffffff, ai1 = 0x7fffffff, ai2 = 0x7fffffff;
    float c0 = 1e30f, c1 = 1e30f, c2 = 1e30f;
    int   ci0 = 0x7fffffff, ci1 = 0x7fffffff, ci2 = 0x7fffffff;
    for (int jj = 0; jj < 256; ++jj) {
        float4 rA = sref[base + jj];
        float4 rB = sref[base + 256 + jj];
        float pA = mul_rn(qx, rA.x);
        float tA = fma_rn(qz, rA.z, fma_rn(qy, rA.y, pA));
        float dA = add_rn(sub_rn(qq, add_rn(tA, tA)), rA.w);
        float pB = mul_rn(qx, rB.x);
        float tB = fma_rn(qz, rB.z, fma_rn(qy, rB.y, pB));
        float dB = add_rn(sub_rn(qq, add_rn(tB, tB)), rB.w);
        if (dA < a2) {
            if (dA < a1) {
                a2 = a1; ai2 = ai1;
                if (dA < a0) { a1 = a0; ai1 = ai0; a0 = dA; ai0 = gbase + jj; }
                else         { a1 = dA; ai1 = gbase + jj; }
            } else { a2 = dA; ai2 = gbase + jj; }
        }
        if (dB < c2) {
            if (dB < c1) {
                c2 = c1; ci2 = ci1;
                if (dB < c0) { c1 = c0; ci1 = ci0; c0 = dB; ci0 = gbase + 256 + jj; }
                else         { c1 = dB; ci1 = gbase + 256 + jj; }
            } else { c2 = dB; ci2 = gbase + 256 + jj; }
        }
    }
    float bd0 = a0, bd1 = a1, bd2 = a2;
    int   bi0 = ai0, bi1 = ai1, bi2 = ai2;
#define LEXINS(d, ji)                                                        \
    if ((d < bd2) || (d == bd2 && ji < bi2)) {                               \
        if ((d < bd1) || (d == bd1 && ji < bi1)) {                           \
            bd2 = bd1; bi2 = bi1;                                            \
            if ((d < bd0) || (d == bd0 && ji < bi0)) {                       \
                bd1 = bd0; bi1 = bi0; bd0 = d; bi0 = ji;                     \
            } else { bd1 = d; bi1 = ji; }                                    \
        } else { bd2 = d; bi2 = ji; }                                        \
    }
    LEXINS(c0, ci0) LEXINS(c1, ci1) LEXINS(c2, ci2)
#pragma unroll
    for (int mask = 1; mask <= 2; mask <<= 1) {
        float pd0 = __shfl_xor(bd0, mask, 64);
        float pd1 = __shfl_xor(bd1, mask, 64);
        float pd2 = __shfl_xor(bd2, mask, 64);
        int   pi0 = __shfl_xor(bi0, mask, 64);
        int   pi1 = __shfl_xor(bi1, mask, 64);
        int   pi2 = __shfl_xor(bi2, mask, 64);
        LEXINS(pd0, pi0) LEXINS(pd1, pi1) LEXINS(pd2, pi2)
    }
#undef LEXINS
    if (sub == 0) {
        float d0s = __fsqrt_rn(fmaxf(bd0, 0.0f));
        float d1s = __fsqrt_rn(fmaxf(bd1, 0.0f));
        float d2s = __fsqrt_rn(fmaxf(bd2, 0.0f));
        float r0 = __fdiv_rn(1.0f, add_rn(d0s, 1e-8f));
        float r1 = __fdiv_rn(1.0f, add_rn(d1s, 1e-8f));
        float r2 = __fdiv_rn(1.0f, add_rn(d2s, 1e-8f));
        float rs = add_rn(add_rn(r0, r1), r2);
        w_out[q * 3 + 0] = __fdiv_rn(r0, rs);
        w_out[q * 3 + 1] = __fdiv_rn(r1, rs);
        w_out[q * 3 + 2] = __fdiv_rn(r2, rs);
        idx_out[q * 3 + 0] = batch * N2B + bi0;
        idx_out[q * 3 + 1] = batch * N2B + bi1;
        idx_out[q * 3 + 2] = batch * N2B + bi2;
    }
}

// ------------------------------------------------- IDW interpolation gather
__global__ __launch_bounds__(128) void interp_kernel(
    const float* __restrict__ points2, const int* __restrict__ idx,
    const float* __restrict__ w, short* __restrict__ interpb)
{
    const int row = blockIdx.x;
    const int c4 = threadIdx.x;
    const int j0 = idx[row * 3 + 0], j1 = idx[row * 3 + 1], j2 = idx[row * 3 + 2];
    const float w0 = w[row * 3 + 0], w1 = w[row * 3 + 1], w2 = w[row * 3 + 2];
    const float4 a = ((const float4*)(points2 + (size_t)j0 * C2))[c4];
    const float4 b = ((const float4*)(points2 + (size_t)j1 * C2))[c4];
    const float4 c = ((const float4*)(points2 + (size_t)j2 * C2))[c4];
    float ox = add_rn(add_rn(mul_rn(a.x, w0), mul_rn(b.x, w1)), mul_rn(c.x, w2));
    float oy = add_rn(add_rn(mul_rn(a.y, w0), mul_rn(b.y, w1)), mul_rn(c.y, w2));
    float oz = add_rn(add_rn(mul_rn(a.z, w0), mul_rn(b.z, w1)), mul_rn(c.z, w2));
    float ow = add_rn(add_rn(mul_rn(a.w, w0), mul_rn(b.w, w1)), mul_rn(c.w, w2));
    short4 o4; o4.x = f2bf(ox); o4.y = f2bf(oy); o4.z = f2bf(oz); o4.w = f2bf(ow);
    *(short4*)(interpb + (size_t)row * C2 + c4 * 4) = o4;
}

// ------------------------------------------------------ prep: casts/transposes
__global__ __launch_bounds__(256) void cast_p1_kernel(
    const float* __restrict__ p1, short* __restrict__ p1b)
{
    const size_t i = ((size_t)blockIdx.x * 256 + threadIdx.x) * 8;
    float4 u0 = *(const float4*)(p1 + i);
    float4 u1 = *(const float4*)(p1 + i + 4);
    bf16x8 v;
    v[0] = f2bf(u0.x); v[1] = f2bf(u0.y); v[2] = f2bf(u0.z); v[3] = f2bf(u0.w);
    v[4] = f2bf(u1.x); v[5] = f2bf(u1.y); v[6] = f2bf(u1.z); v[7] = f2bf(u1.w);
    *(bf16x8*)(p1b + i) = v;
}

// W[K][N] f32 -> WT[N][K] bf16
__global__ __launch_bounds__(256) void transpose_w_kernel(
    const float* __restrict__ Win, short* __restrict__ WT, int K, int N)
{
    const int e = blockIdx.x * 256 + threadIdx.x;
    const int k = e / N, n = e % N;
    WT[(size_t)n * K + k] = f2bf(Win[e]);
}

// --------------------------------------------- bf16 MFMA GEMMs (128x128 tile)
// Epilogue fuses BN-stats: per-block column partials of (v, v^2) into
// psum/psq[512][256] via shfl_xor(16,32) wave reduce + LDS cross-wave.
#define LDP 40

// Shared epilogue: writes y + per-block-row BN partial sums.
// rows: rowb = row0 + wr*64 + m*16 + (lane>>4)*4 + j ; col = col0+wc*64+n*16+l16
#define GEMM_EPILOGUE(YOUT)                                                   \
    __shared__ float redS[2][2][64], redQ[2][2][64];                          \
    _Pragma("unroll")                                                         \
    for (int n = 0; n < 4; ++n) {                                             \
        const int col = col0 + wc * 64 + n * 16 + l16;                        \
        const float bv = bias[col];                                           \
        float s = 0.f, qa = 0.f;                                              \
        _Pragma("unroll")                                                     \
        for (int m = 0; m < 4; ++m) {                                         \
            const int rowb = row0 + wr * 64 + m * 16 + (lane >> 4) * 4;       \
            _Pragma("unroll")                                                 \
            for (int j = 0; j < 4; ++j) {                                     \
                float v = acc[m][n][j] + bv;                                  \
                (YOUT)[(size_t)(rowb + j) * HID + col] = v;                   \
                s += v; qa = fmaf(v, v, qa);                                  \
            }                                                                 \
        }                                                                     \
        s += __shfl_xor(s, 16, 64);  s += __shfl_xor(s, 32, 64);              \
        qa += __shfl_xor(qa, 16, 64); qa += __shfl_xor(qa, 32, 64);           \
        if ((lane >> 4) == 0) {                                               \
            redS[wr][wc][n * 16 + l16] = s;                                   \
            redQ[wr][wc][n * 16 + l16] = qa;                                  \
        }                                                                     \
    }                                                                         \
    __syncthreads();                                                          \
    if (tid < 128) {                                                          \
        const int wcf = tid >> 6, cf = tid & 63;                              \
        float s = redS[0][wcf][cf] + redS[1][wcf][cf];                        \
        float qa = redQ[0][wcf][cf] + redQ[1][wcf][cf];                       \
        const int gcol = col0 + wcf * 64 + cf;                                \
        psum[(size_t)blockIdx.y * HID + gcol] = s;                            \
        psq[(size_t)blockIdx.y * HID + gcol] = qa;                            \
    }

// y1 = concat(points1, interp) @ W1 + b1
__global__ __launch_bounds__(256) void gemm1m_kernel(
    const short* __restrict__ p1b, const short* __restrict__ interpb,
    const short* __restrict__ w1t, const float* __restrict__ bias,
    float* __restrict__ y1, float* __restrict__ psum, float* __restrict__ psq)
{
    __shared__ short As[128][LDP];
    __shared__ short Bs[128][LDP];
    const int tid = threadIdx.x;
    const int lane = tid & 63, wv = tid >> 6;
    const int wr = wv >> 1, wc = wv & 1;
    const int l16 = lane & 15, kh = (lane >> 4) * 8;
    const int row0 = blockIdx.y * 128, col0 = blockIdx.x * 128;
    f32x4 acc[4][4];
#pragma unroll
    for (int m = 0; m < 4; ++m)
#pragma unroll
        for (int n = 0; n < 4; ++n) acc[m][n] = (f32x4){0.f, 0.f, 0.f, 0.f};

    const int c0 = tid * 2;
    const int r0c = c0 >> 2, kc0 = (c0 & 3) * 8;
    const int r1c = (c0 + 1) >> 2, kc1 = ((c0 + 1) & 3) * 8;

    for (int kt = 0; kt < K1 / 32; ++kt) {
        const int k0 = kt * 32;
        bf16x8 va, vb, wa, wb;
        if (k0 < C1) {
            va = *(const bf16x8*)(p1b + (size_t)(row0 + r0c) * C1 + k0 + kc0);
            vb = *(const bf16x8*)(p1b + (size_t)(row0 + r1c) * C1 + k0 + kc1);
        } else {
            va = *(const bf16x8*)(interpb + (size_t)(row0 + r0c) * C2 + (k0 - C1) + kc0);
            vb = *(const bf16x8*)(interpb + (size_t)(row0 + r1c) * C2 + (k0 - C1) + kc1);
        }
        wa = *(const bf16x8*)(w1t + (size_t)(col0 + r0c) * K1 + k0 + kc0);
        wb = *(const bf16x8*)(w1t + (size_t)(col0 + r1c) * K1 + k0 + kc1);
        __syncthreads();
        *(bf16x8*)(&As[r0c][kc0]) = va;
        *(bf16x8*)(&As[r1c][kc1]) = vb;
        *(bf16x8*)(&Bs[r0c][kc0]) = wa;
        *(bf16x8*)(&Bs[r1c][kc1]) = wb;
        __syncthreads();

        bf16x8 af[4], bf[4];
#pragma unroll
        for (int m = 0; m < 4; ++m)
            af[m] = *(const bf16x8*)(&As[wr * 64 + m * 16 + l16][kh]);
#pragma unroll
        for (int n = 0; n < 4; ++n)
            bf[n] = *(const bf16x8*)(&Bs[wc * 64 + n * 16 + l16][kh]);
#pragma unroll
        for (int m = 0; m < 4; ++m)
#pragma unroll
            for (int n = 0; n < 4; ++n)
                acc[m][n] = __builtin_amdgcn_mfma_f32_16x16x32_bf16(
                    af[m], bf[n], acc[m][n], 0, 0, 0);
    }
    GEMM_EPILOGUE(y1)
}

// y2 = relu(bn(y1)) @ W2 + b2
__global__ __launch_bounds__(256) void gemm2m_kernel(
    const float* __restrict__ y1, const float* __restrict__ scale,
    const float* __restrict__ shift, const short* __restrict__ w2t,
    const float* __restrict__ bias, float* __restrict__ y2,
    float* __restrict__ psum, float* __restrict__ psq)
{
    __shared__ short As[128][LDP];
    __shared__ short Bs[128][LDP];
    const int tid = threadIdx.x;
    const int lane = tid & 63, wv = tid >> 6;
    const int wr = wv >> 1, wc = wv & 1;
    const int l16 = lane & 15, kh = (lane >> 4) * 8;
    const int row0 = blockIdx.y * 128, col0 = blockIdx.x * 128;
    f32x4 acc[4][4];
#pragma unroll
    for (int m = 0; m < 4; ++m)
#pragma unroll
        for (int n = 0; n < 4; ++n) acc[m][n] = (f32x4){0.f, 0.f, 0.f, 0.f};

    const int c0 = tid * 2;
    const int r0c = c0 >> 2, kc0 = (c0 & 3) * 8;
    const int r1c = (c0 + 1) >> 2, kc1 = ((c0 + 1) & 3) * 8;

    for (int kt = 0; kt < HID / 32; ++kt) {
        const int k0 = kt * 32;
        float4 u0 = *(const float4*)(y1 + (size_t)(row0 + r0c) * HID + k0 + kc0);
        float4 u1 = *(const float4*)(y1 + (size_t)(row0 + r0c) * HID + k0 + kc0 + 4);
        float4 s0 = *(const float4*)(scale + k0 + kc0);
        float4 s1 = *(const float4*)(scale + k0 + kc0 + 4);
        float4 h0 = *(const float4*)(shift + k0 + kc0);
        float4 h1 = *(const float4*)(shift + k0 + kc0 + 4);
        bf16x8 va;
        va[0] = f2bf(fmaxf(fmaf(u0.x, s0.x, h0.x), 0.f));
        va[1] = f2bf(fmaxf(fmaf(u0.y, s0.y, h0.y), 0.f));
        va[2] = f2bf(fmaxf(fmaf(u0.z, s0.z, h0.z), 0.f));
        va[3] = f2bf(fmaxf(fmaf(u0.w, s0.w, h0.w), 0.f));
        va[4] = f2bf(fmaxf(fmaf(u1.x, s1.x, h1.x), 0.f));
        va[5] = f2bf(fmaxf(fmaf(u1.y, s1.y, h1.y), 0.f));
        va[6] = f2bf(fmaxf(fmaf(u1.z, s1.z, h1.z), 0.f));
        va[7] = f2bf(fmaxf(fmaf(u1.w, s1.w, h1.w), 0.f));
        float4 u2 = *(const float4*)(y1 + (size_t)(row0 + r1c) * HID + k0 + kc1);
        float4 u3 = *(const float4*)(y1 + (size_t)(row0 + r1c) * HID + k0 + kc1 + 4);
        float4 s2 = *(const float4*)(scale + k0 + kc1);
        float4 s3 = *(const float4*)(scale + k0 + kc1 + 4);
        float4 h2 = *(const float4*)(shift + k0 + kc1);
        float4 h3 = *(const float4*)(shift + k0 + kc1 + 4);
        bf16x8 vb;
        vb[0] = f2bf(fmaxf(fmaf(u2.x, s2.x, h2.x), 0.f));
        vb[1] = f2bf(fmaxf(fmaf(u2.y, s2.y, h2.y), 0.f));
        vb[2] = f2bf(fmaxf(fmaf(u2.z, s2.z, h2.z), 0.f));
        vb[3] = f2bf(fmaxf(fmaf(u2.w, s2.w, h2.w), 0.f));
        vb[4] = f2bf(fmaxf(fmaf(u3.x, s3.x, h3.x), 0.f));
        vb[5] = f2bf(fmaxf(fmaf(u3.y, s3.y, h3.y), 0.f));
        vb[6] = f2bf(fmaxf(fmaf(u3.z, s3.z, h3.z), 0.f));
        vb[7] = f2bf(fmaxf(fmaf(u3.w, s3.w, h3.w), 0.f));
        bf16x8 wa = *(const bf16x8*)(w2t + (size_t)(col0 + r0c) * HID + k0 + kc0);
        bf16x8 wb = *(const bf16x8*)(w2t + (size_t)(col0 + r1c) * HID + k0 + kc1);
        __syncthreads();
        *(bf16x8*)(&As[r0c][kc0]) = va;
        *(bf16x8*)(&As[r1c][kc1]) = vb;
        *(bf16x8*)(&Bs[r0c][kc0]) = wa;
        *(bf16x8*)(&Bs[r1c][kc1]) = wb;
        __syncthreads();

        bf16x8 af[4], bf[4];
#pragma unroll
        for (int m = 0; m < 4; ++m)
            af[m] = *(const bf16x8*)(&As[wr * 64 + m * 16 + l16][kh]);
#pragma unroll
        for (int n = 0; n < 4; ++n)
            bf[n] = *(const bf16x8*)(&Bs[wc * 64 + n * 16 + l16][kh]);
#pragma unroll
        for (int m = 0; m < 4; ++m)
#pragma unroll
            for (int n = 0; n < 4; ++n)
                acc[m][n] = __builtin_amdgcn_mfma_f32_16x16x32_bf16(
                    af[m], bf[n], acc[m][n], 0, 0, 0);
    }
    GEMM_EPILOGUE(y2)
}

// ----------------------------------------------------- BN finalize (512 rows)
__global__ __launch_bounds__(256) void bn_finalize_kernel(
    const float* __restrict__ psum, const float* __restrict__ psq,
    const float* __restrict__ g, const float* __restrict__ be,
    float* __restrict__ scale, float* __restrict__ shift)
{
    const int c = threadIdx.x;
    float s = 0.0f, q = 0.0f;
    for (int b = 0; b < 512; ++b) { s += psum[b * HID + c]; q += psq[b * HID + c]; }
    const float inv_n = 1.0f / (float)N1T;
    const float mu = s * inv_n;
    const float var = fmaxf(q * inv_n - mu * mu, 0.0f);
    const float sc = g[c] * rsqrtf(var + BN_EPS);
    scale[c] = sc;
    shift[c] = be[c] - mu * sc;
}

// --------------------------------------------------------- final BN+ReLU
__global__ __launch_bounds__(256) void bn_apply_kernel(
    const float* __restrict__ y, const float* __restrict__ scale,
    const float* __restrict__ shift, float* __restrict__ out)
{
    const size_t i = (size_t)blockIdx.x * 256 + threadIdx.x;
    const int c4 = (int)(i & 63) * 4;
    float4 v = ((const float4*)y)[i];
    const float4 sc = *(const float4*)(scale + c4);
    const float4 sh = *(const float4*)(shift + c4);
    float4 o;
    o.x = fmaxf(fmaf(v.x, sc.x, sh.x), 0.0f);
    o.y = fmaxf(fmaf(v.y, sc.y, sh.y), 0.0f);
    o.z = fmaxf(fmaf(v.z, sc.z, sh.z), 0.0f);
    o.w = fmaxf(fmaf(v.w, sc.w, sh.w), 0.0f);
    ((float4*)out)[i] = o;
}

// -------------------------------------------------------------- launcher
extern "C" void kernel_launch(void* const* d_in, const int* in_sizes, int n_in,
                              void* d_out, int out_size, void* d_ws, size_t ws_size,
                              hipStream_t stream)
{
    const float* xyz1    = (const float*)d_in[0];
    const float* points1 = (const float*)d_in[1];
    const float* xyz2    = (const float*)d_in[2];
    const float* points2 = (const float*)d_in[3];
    const float* W1  = (const float*)d_in[6];
    const float* b1  = (const float*)d_in[7];
    const float* g1  = (const float*)d_in[8];
    const float* be1 = (const float*)d_in[9];
    const float* W2  = (const float*)d_in[10];
    const float* b2  = (const float*)d_in[11];
    const float* g2  = (const float*)d_in[12];
    const float* be2 = (const float*)d_in[13];
    float* out = (float*)d_out;

    char* ws = (char*)d_ws;
    short* interpb = (short*)ws;                   // bf16 [N1,512]; y2 f32 later
    float* y1      = (float*)(ws + 67108864);
    short* p1b     = (short*)(ws + 134217728);
    size_t off     = 134217728 + 33554432;
    short* w1t     = (short*)(ws + off); off += (size_t)K1 * HID * 2;
    short* w2t     = (short*)(ws + off); off += (size_t)HID * HID * 2;
    int*   idx     = (int*)(ws + off);   off += (size_t)N1T * 3 * 4;
    float* w       = (float*)(ws + off); off += (size_t)N1T * 3 * 4;
    float* psum    = (float*)(ws + off); off += 512 * 256 * 4;
    float* psq     = (float*)(ws + off); off += 512 * 256 * 4;
    float* scale1  = (float*)(ws + off); off += 256 * 4;
    float* shift1  = (float*)(ws + off); off += 256 * 4;
    float* scale2  = (float*)(ws + off); off += 256 * 4;
    float* shift2  = (float*)(ws + off); off += 256 * 4;
    float* y2 = (float*)interpb;  // reuse: interp dead after gemm1

    cast_p1_kernel<<<N1T * C1 / 8 / 256, 256, 0, stream>>>(points1, p1b);
    transpose_w_kernel<<<K1 * HID / 256, 256, 0, stream>>>(W1, w1t, K1, HID);
    transpose_w_kernel<<<HID * HID / 256, 256, 0, stream>>>(W2, w2t, HID, HID);
    knn_kernel<<<1024, 256, 0, stream>>>(xyz1, xyz2, idx, w);
    interp_kernel<<<N1T, 128, 0, stream>>>(points2, idx, w, interpb);
    gemm1m_kernel<<<dim3(HID / 128, N1T / 128), 256, 0, stream>>>(
        p1b, interpb, w1t, b1, y1, psum, psq);
    bn_finalize_kernel<<<1, 256, 0, stream>>>(psum, psq, g1, be1, scale1, shift1);
    gemm2m_kernel<<<dim3(HID / 128, N1T / 128), 256, 0, stream>>>(
        y1, scale1, shift1, w2t, b2, y2, psum, psq);
    bn_finalize_kernel<<<1, 256, 0, stream>>>(psum, psq, g2, be2, scale2, shift2);
    bn_apply_kernel<<<(N1T * HID / 4) / 256, 256, 0, stream>>>(y2, scale2, shift2, out);
}

// Round 14
// 290.048 us; speedup vs baseline: 1.4939x; 1.0051x over previous
//
#include <hip/hip_runtime.h>
#include <math.h>

#define N1T 65536
#define N2T 16384
#define BSZ 8
#define N1B 8192   // points per batch in xyz1
#define N2B 2048   // points per batch in xyz2
#define C1 256
#define C2 512
#define K1 768     // C1 + C2
#define HID 256
#define BN_EPS 1e-5f

typedef short bf16x8 __attribute__((ext_vector_type(8)));
typedef float f32x4 __attribute__((ext_vector_type(4)));

// Exact single-rounded f32 ops via ISA — immune to -ffast-math / contraction.
__device__ __forceinline__ float mul_rn(float a, float b) {
    float r; asm("v_mul_f32 %0, %1, %2" : "=v"(r) : "v"(a), "v"(b)); return r;
}
__device__ __forceinline__ float add_rn(float a, float b) {
    float r; asm("v_add_f32 %0, %1, %2" : "=v"(r) : "v"(a), "v"(b)); return r;
}
__device__ __forceinline__ float sub_rn(float a, float b) {
    float r; asm("v_sub_f32 %0, %1, %2" : "=v"(r) : "v"(a), "v"(b)); return r;
}
__device__ __forceinline__ float fma_rn(float a, float b, float c) {
    float r; asm("v_fma_f32 %0, %1, %2, %3" : "=v"(r) : "v"(a), "v"(b), "v"(c)); return r;
}
// f32 -> bf16 round-to-nearest-even
__device__ __forceinline__ short f2bf(float f) {
    unsigned u = __builtin_bit_cast(unsigned, f);
    u += 0x7fffu + ((u >> 16) & 1u);
    return (short)(u >> 16);
}
// bf16 -> f32 (exact)
__device__ __forceinline__ float bf2f(short s) {
    return __builtin_bit_cast(float, ((unsigned)(unsigned short)s) << 16);
}

// ---------------------------------------------------------------- KNN-3
// FROZEN arithmetic (r9): d2 = (qq - 2*dot) + kk, nofma qq/kk, fma-asc dot.
// r14: branchless top-3 insert (3 cmp + 10 cndmask, strict-< semantics
// identical) — wave-wide insert branch was taken ~74% of iterations.
__global__ __launch_bounds__(256) void knn_kernel(
    const float* __restrict__ xyz1, const float* __restrict__ xyz2,
    int* __restrict__ idx_out, float* __restrict__ w_out)
{
    __shared__ float4 sref[N2B + 4];         // padded: pos = p + p/512
    const int tid = threadIdx.x;
    const int qbase = blockIdx.x * 64;       // 1024 blocks x 64 queries
    const int batch = qbase / N1B;
    const float* k2 = xyz2 + (size_t)batch * N2B * 3;
    for (int p = tid; p < N2B; p += 256) {
        float x = k2[3 * p], y = k2[3 * p + 1], z = k2[3 * p + 2];
        float kk = add_rn(add_rn(mul_rn(x, x), mul_rn(y, y)), mul_rn(z, z));
        sref[p + (p >> 9)] = make_float4(x, y, z, kk);
    }
    __syncthreads();

    const int q = qbase + (tid >> 2);
    const int sub = tid & 3;
    const float qx = xyz1[q * 3 + 0], qy = xyz1[q * 3 + 1], qz = xyz1[q * 3 + 2];
    const float qq = add_rn(add_rn(mul_rn(qx, qx), mul_rn(qy, qy)), mul_rn(qz, qz));

    const int base = sub * 513;              // padded LDS base
    const int gbase = sub * 512;             // global index base
    float a0 = 1e30f, a1 = 1e30f, a2 = 1e30f;
    int   ai0 = 0x7fffffff, ai1 = 0x7fffffff, ai2 = 0x7fffffff;
    float c0 = 1e30f, c1 = 1e30f, c2 = 1e30f;
    int   ci0 = 0x7fffffff, ci1 = 0x7fffffff, ci2 = 0x7fffffff;
    for (int jj = 0; jj < 256; ++jj) {
        float4 rA = sref[base + jj];
        float4 rB = sref[base + 256 + jj];
        // stream A
        {
            float p0 = mul_rn(qx, rA.x);
            float dt = fma_rn(qz, rA.z, fma_rn(qy, rA.y, p0));
            float d  = add_rn(sub_rn(qq, add_rn(dt, dt)), rA.w);
            const int j = gbase + jj;
            bool lt2 = d < a2, lt1 = d < a1, lt0 = d < a0;
            a2 = lt1 ? a1 : (lt2 ? d : a2); ai2 = lt1 ? ai1 : (lt2 ? j : ai2);
            a1 = lt0 ? a0 : (lt1 ? d : a1); ai1 = lt0 ? ai0 : (lt1 ? j : ai1);
            a0 = lt0 ? d : a0;              ai0 = lt0 ? j : ai0;
        }
        // stream B
        {
            float p0 = mul_rn(qx, rB.x);
            float dt = fma_rn(qz, rB.z, fma_rn(qy, rB.y, p0));
            float d  = add_rn(sub_rn(qq, add_rn(dt, dt)), rB.w);
            const int j = gbase + 256 + jj;
            bool lt2 = d < c2, lt1 = d < c1, lt0 = d < c0;
            c2 = lt1 ? c1 : (lt2 ? d : c2); ci2 = lt1 ? ci1 : (lt2 ? j : ci2);
            c1 = lt0 ? c0 : (lt1 ? d : c1); ci1 = lt0 ? ci0 : (lt1 ? j : ci1);
            c0 = lt0 ? d : c0;              ci0 = lt0 ? j : ci0;
        }
    }
    float bd0 = a0, bd1 = a1, bd2 = a2;
    int   bi0 = ai0, bi1 = ai1, bi2 = ai2;
#define LEXINS(d, ji)                                                        \
    if ((d < bd2) || (d == bd2 && ji < bi2)) {                               \
        if ((d < bd1) || (d == bd1 && ji < bi1)) {                           \
            bd2 = bd1; bi2 = bi1;                                            \
            if ((d < bd0) || (d == bd0 && ji < bi0)) {                       \
                bd1 = bd0; bi1 = bi0; bd0 = d; bi0 = ji;                     \
            } else { bd1 = d; bi1 = ji; }                                    \
        } else { bd2 = d; bi2 = ji; }                                        \
    }
    LEXINS(c0, ci0) LEXINS(c1, ci1) LEXINS(c2, ci2)
#pragma unroll
    for (int mask = 1; mask <= 2; mask <<= 1) {
        float pd0 = __shfl_xor(bd0, mask, 64);
        float pd1 = __shfl_xor(bd1, mask, 64);
        float pd2 = __shfl_xor(bd2, mask, 64);
        int   pi0 = __shfl_xor(bi0, mask, 64);
        int   pi1 = __shfl_xor(bi1, mask, 64);
        int   pi2 = __shfl_xor(bi2, mask, 64);
        LEXINS(pd0, pi0) LEXINS(pd1, pi1) LEXINS(pd2, pi2)
    }
#undef LEXINS
    if (sub == 0) {
        float d0s = __fsqrt_rn(fmaxf(bd0, 0.0f));
        float d1s = __fsqrt_rn(fmaxf(bd1, 0.0f));
        float d2s = __fsqrt_rn(fmaxf(bd2, 0.0f));
        float r0 = __fdiv_rn(1.0f, add_rn(d0s, 1e-8f));
        float r1 = __fdiv_rn(1.0f, add_rn(d1s, 1e-8f));
        float r2 = __fdiv_rn(1.0f, add_rn(d2s, 1e-8f));
        float rs = add_rn(add_rn(r0, r1), r2);
        w_out[q * 3 + 0] = __fdiv_rn(r0, rs);
        w_out[q * 3 + 1] = __fdiv_rn(r1, rs);
        w_out[q * 3 + 2] = __fdiv_rn(r2, rs);
        idx_out[q * 3 + 0] = batch * N2B + bi0;
        idx_out[q * 3 + 1] = batch * N2B + bi1;
        idx_out[q * 3 + 2] = batch * N2B + bi2;
    }
}

// ------------------------------------------------- IDW gather (bf16 points2)
// writes into fused A buffer abuf[N1][768], columns 256:768
__global__ __launch_bounds__(128) void interp_kernel(
    const short* __restrict__ p2b, const int* __restrict__ idx,
    const float* __restrict__ w, short* __restrict__ abuf)
{
    const int row = blockIdx.x;
    const int c4 = threadIdx.x;          // 4 cols per thread
    const int j0 = idx[row * 3 + 0], j1 = idx[row * 3 + 1], j2 = idx[row * 3 + 2];
    const float w0 = w[row * 3 + 0], w1 = w[row * 3 + 1], w2 = w[row * 3 + 2];
    short4 a4 = *(const short4*)(p2b + (size_t)j0 * C2 + c4 * 4);
    short4 b4 = *(const short4*)(p2b + (size_t)j1 * C2 + c4 * 4);
    short4 d4 = *(const short4*)(p2b + (size_t)j2 * C2 + c4 * 4);
    short4 o4;
    o4.x = f2bf(fmaf(bf2f(a4.x), w0, fmaf(bf2f(b4.x), w1, bf2f(d4.x) * w2)));
    o4.y = f2bf(fmaf(bf2f(a4.y), w0, fmaf(bf2f(b4.y), w1, bf2f(d4.y) * w2)));
    o4.z = f2bf(fmaf(bf2f(a4.z), w0, fmaf(bf2f(b4.z), w1, bf2f(d4.z) * w2)));
    o4.w = f2bf(fmaf(bf2f(a4.w), w0, fmaf(bf2f(b4.w), w1, bf2f(d4.w) * w2)));
    *(short4*)(abuf + (size_t)row * K1 + C1 + c4 * 4) = o4;
}

// ------------------------------------------------------ prep kernels
// points1 f32 -> abuf[N1][768] cols 0:256 (bf16)
__global__ __launch_bounds__(256) void cast_p1_kernel(
    const float* __restrict__ p1, short* __restrict__ abuf)
{
    const size_t i = ((size_t)blockIdx.x * 256 + threadIdx.x) * 8;
    const size_t row = i >> 8;           // / C1
    const int col = (int)(i & 255);
    float4 u0 = *(const float4*)(p1 + i);
    float4 u1 = *(const float4*)(p1 + i + 4);
    bf16x8 v;
    v[0] = f2bf(u0.x); v[1] = f2bf(u0.y); v[2] = f2bf(u0.z); v[3] = f2bf(u0.w);
    v[4] = f2bf(u1.x); v[5] = f2bf(u1.y); v[6] = f2bf(u1.z); v[7] = f2bf(u1.w);
    *(bf16x8*)(abuf + row * K1 + col) = v;
}

// points2 f32 -> bf16 flat
__global__ __launch_bounds__(256) void cast_p2_kernel(
    const float* __restrict__ p2, short* __restrict__ p2b)
{
    const size_t i = ((size_t)blockIdx.x * 256 + threadIdx.x) * 8;
    float4 u0 = *(const float4*)(p2 + i);
    float4 u1 = *(const float4*)(p2 + i + 4);
    bf16x8 v;
    v[0] = f2bf(u0.x); v[1] = f2bf(u0.y); v[2] = f2bf(u0.z); v[3] = f2bf(u0.w);
    v[4] = f2bf(u1.x); v[5] = f2bf(u1.y); v[6] = f2bf(u1.z); v[7] = f2bf(u1.w);
    *(bf16x8*)(p2b + i) = v;
}

// W[K][N] f32 -> WT[N][K] bf16
__global__ __launch_bounds__(256) void transpose_w_kernel(
    const float* __restrict__ Win, short* __restrict__ WT, int K, int N)
{
    const int e = blockIdx.x * 256 + threadIdx.x;
    const int k = e / N, n = e % N;
    WT[(size_t)n * K + k] = f2bf(Win[e]);
}

// --------------------------------------------- bf16 MFMA GEMMs (128x128 tile)
#define LDP 40

// Epilogue: bias add, store via STORE_STMT(v, rowb+j, col), BN partials.
#define GEMM_EPILOGUE(STORE_STMT)                                             \
    __shared__ float redS[2][2][64], redQ[2][2][64];                          \
    _Pragma("unroll")                                                         \
    for (int n = 0; n < 4; ++n) {                                             \
        const int col = col0 + wc * 64 + n * 16 + l16;                        \
        const float bv = bias[col];                                           \
        float s = 0.f, qa = 0.f;                                              \
        _Pragma("unroll")                                                     \
        for (int m = 0; m < 4; ++m) {                                         \
            const int rowb = row0 + wr * 64 + m * 16 + (lane >> 4) * 4;       \
            _Pragma("unroll")                                                 \
            for (int j = 0; j < 4; ++j) {                                     \
                float v = acc[m][n][j] + bv;                                  \
                STORE_STMT;                                                   \
                s += v; qa = fmaf(v, v, qa);                                  \
            }                                                                 \
        }                                                                     \
        s += __shfl_xor(s, 16, 64);  s += __shfl_xor(s, 32, 64);              \
        qa += __shfl_xor(qa, 16, 64); qa += __shfl_xor(qa, 32, 64);           \
        if ((lane >> 4) == 0) {                                               \
            redS[wr][wc][n * 16 + l16] = s;                                   \
            redQ[wr][wc][n * 16 + l16] = qa;                                  \
        }                                                                     \
    }                                                                         \
    __syncthreads();                                                          \
    if (tid < 128) {                                                          \
        const int wcf = tid >> 6, cf = tid & 63;                              \
        float s = redS[0][wcf][cf] + redS[1][wcf][cf];                        \
        float qa = redQ[0][wcf][cf] + redQ[1][wcf][cf];                       \
        const int gcol = col0 + wcf * 64 + cf;                                \
        psum[(size_t)blockIdx.y * HID + gcol] = s;                            \
        psq[(size_t)blockIdx.y * HID + gcol] = qa;                            \
    }

// y1b = bf16( abuf @ W1 + b1 ), stats from f32 acc
__global__ __launch_bounds__(256) void gemm1m_kernel(
    const short* __restrict__ abuf, const short* __restrict__ w1t,
    const float* __restrict__ bias, short* __restrict__ y1b,
    float* __restrict__ psum, float* __restrict__ psq)
{
    __shared__ short As[128][LDP];
    __shared__ short Bs[128][LDP];
    const int tid = threadIdx.x;
    const int lane = tid & 63, wv = tid >> 6;
    const int wr = wv >> 1, wc = wv & 1;
    const int l16 = lane & 15, kh = (lane >> 4) * 8;
    const int row0 = blockIdx.y * 128, col0 = blockIdx.x * 128;
    f32x4 acc[4][4];
#pragma unroll
    for (int m = 0; m < 4; ++m)
#pragma unroll
        for (int n = 0; n < 4; ++n) acc[m][n] = (f32x4){0.f, 0.f, 0.f, 0.f};

    const int c0 = tid * 2;
    const int r0c = c0 >> 2, kc0 = (c0 & 3) * 8;
    const int r1c = (c0 + 1) >> 2, kc1 = ((c0 + 1) & 3) * 8;

    for (int kt = 0; kt < K1 / 32; ++kt) {
        const int k0 = kt * 32;
        bf16x8 va = *(const bf16x8*)(abuf + (size_t)(row0 + r0c) * K1 + k0 + kc0);
        bf16x8 vb = *(const bf16x8*)(abuf + (size_t)(row0 + r1c) * K1 + k0 + kc1);
        bf16x8 wa = *(const bf16x8*)(w1t + (size_t)(col0 + r0c) * K1 + k0 + kc0);
        bf16x8 wb = *(const bf16x8*)(w1t + (size_t)(col0 + r1c) * K1 + k0 + kc1);
        __syncthreads();
        *(bf16x8*)(&As[r0c][kc0]) = va;
        *(bf16x8*)(&As[r1c][kc1]) = vb;
        *(bf16x8*)(&Bs[r0c][kc0]) = wa;
        *(bf16x8*)(&Bs[r1c][kc1]) = wb;
        __syncthreads();

        bf16x8 af[4], bf[4];
#pragma unroll
        for (int m = 0; m < 4; ++m)
            af[m] = *(const bf16x8*)(&As[wr * 64 + m * 16 + l16][kh]);
#pragma unroll
        for (int n = 0; n < 4; ++n)
            bf[n] = *(const bf16x8*)(&Bs[wc * 64 + n * 16 + l16][kh]);
#pragma unroll
        for (int m = 0; m < 4; ++m)
#pragma unroll
            for (int n = 0; n < 4; ++n)
                acc[m][n] = __builtin_amdgcn_mfma_f32_16x16x32_bf16(
                    af[m], bf[n], acc[m][n], 0, 0, 0);
    }
    GEMM_EPILOGUE(y1b[(size_t)(rowb + j) * HID + col] = f2bf(v))
}

// y2 = relu(bn(y1b)) @ W2 + b2   (f32 out for final bn_apply)
__global__ __launch_bounds__(256) void gemm2m_kernel(
    const short* __restrict__ y1b, const float* __restrict__ scale,
    const float* __restrict__ shift, const short* __restrict__ w2t,
    const float* __restrict__ bias, float* __restrict__ y2,
    float* __restrict__ psum, float* __restrict__ psq)
{
    __shared__ short As[128][LDP];
    __shared__ short Bs[128][LDP];
    const int tid = threadIdx.x;
    const int lane = tid & 63, wv = tid >> 6;
    const int wr = wv >> 1, wc = wv & 1;
    const int l16 = lane & 15, kh = (lane >> 4) * 8;
    const int row0 = blockIdx.y * 128, col0 = blockIdx.x * 128;
    f32x4 acc[4][4];
#pragma unroll
    for (int m = 0; m < 4; ++m)
#pragma unroll
        for (int n = 0; n < 4; ++n) acc[m][n] = (f32x4){0.f, 0.f, 0.f, 0.f};

    const int c0 = tid * 2;
    const int r0c = c0 >> 2, kc0 = (c0 & 3) * 8;
    const int r1c = (c0 + 1) >> 2, kc1 = ((c0 + 1) & 3) * 8;

    for (int kt = 0; kt < HID / 32; ++kt) {
        const int k0 = kt * 32;
        bf16x8 x0 = *(const bf16x8*)(y1b + (size_t)(row0 + r0c) * HID + k0 + kc0);
        bf16x8 x1 = *(const bf16x8*)(y1b + (size_t)(row0 + r1c) * HID + k0 + kc1);
        float4 s0 = *(const float4*)(scale + k0 + kc0);
        float4 s1 = *(const float4*)(scale + k0 + kc0 + 4);
        float4 h0 = *(const float4*)(shift + k0 + kc0);
        float4 h1 = *(const float4*)(shift + k0 + kc0 + 4);
        float4 s2 = *(const float4*)(scale + k0 + kc1);
        float4 s3 = *(const float4*)(scale + k0 + kc1 + 4);
        float4 h2 = *(const float4*)(shift + k0 + kc1);
        float4 h3 = *(const float4*)(shift + k0 + kc1 + 4);
        bf16x8 va, vb;
        va[0] = f2bf(fmaxf(fmaf(bf2f(x0[0]), s0.x, h0.x), 0.f));
        va[1] = f2bf(fmaxf(fmaf(bf2f(x0[1]), s0.y, h0.y), 0.f));
        va[2] = f2bf(fmaxf(fmaf(bf2f(x0[2]), s0.z, h0.z), 0.f));
        va[3] = f2bf(fmaxf(fmaf(bf2f(x0[3]), s0.w, h0.w), 0.f));
        va[4] = f2bf(fmaxf(fmaf(bf2f(x0[4]), s1.x, h1.x), 0.f));
        va[5] = f2bf(fmaxf(fmaf(bf2f(x0[5]), s1.y, h1.y), 0.f));
        va[6] = f2bf(fmaxf(fmaf(bf2f(x0[6]), s1.z, h1.z), 0.f));
        va[7] = f2bf(fmaxf(fmaf(bf2f(x0[7]), s1.w, h1.w), 0.f));
        vb[0] = f2bf(fmaxf(fmaf(bf2f(x1[0]), s2.x, h2.x), 0.f));
        vb[1] = f2bf(fmaxf(fmaf(bf2f(x1[1]), s2.y, h2.y), 0.f));
        vb[2] = f2bf(fmaxf(fmaf(bf2f(x1[2]), s2.z, h2.z), 0.f));
        vb[3] = f2bf(fmaxf(fmaf(bf2f(x1[3]), s2.w, h2.w), 0.f));
        vb[4] = f2bf(fmaxf(fmaf(bf2f(x1[4]), s3.x, h3.x), 0.f));
        vb[5] = f2bf(fmaxf(fmaf(bf2f(x1[5]), s3.y, h3.y), 0.f));
        vb[6] = f2bf(fmaxf(fmaf(bf2f(x1[6]), s3.z, h3.z), 0.f));
        vb[7] = f2bf(fmaxf(fmaf(bf2f(x1[7]), s3.w, h3.w), 0.f));
        bf16x8 wa = *(const bf16x8*)(w2t + (size_t)(col0 + r0c) * HID + k0 + kc0);
        bf16x8 wb = *(const bf16x8*)(w2t + (size_t)(col0 + r1c) * HID + k0 + kc1);
        __syncthreads();
        *(bf16x8*)(&As[r0c][kc0]) = va;
        *(bf16x8*)(&As[r1c][kc1]) = vb;
        *(bf16x8*)(&Bs[r0c][kc0]) = wa;
        *(bf16x8*)(&Bs[r1c][kc1]) = wb;
        __syncthreads();

        bf16x8 af[4], bf[4];
#pragma unroll
        for (int m = 0; m < 4; ++m)
            af[m] = *(const bf16x8*)(&As[wr * 64 + m * 16 + l16][kh]);
#pragma unroll
        for (int n = 0; n < 4; ++n)
            bf[n] = *(const bf16x8*)(&Bs[wc * 64 + n * 16 + l16][kh]);
#pragma unroll
        for (int m = 0; m < 4; ++m)
#pragma unroll
            for (int n = 0; n < 4; ++n)
                acc[m][n] = __builtin_amdgcn_mfma_f32_16x16x32_bf16(
                    af[m], bf[n], acc[m][n], 0, 0, 0);
    }
    GEMM_EPILOGUE(y2[(size_t)(rowb + j) * HID + col] = v)
}

// ----------------------------------------------------- BN finalize (512 rows)
__global__ __launch_bounds__(256) void bn_finalize_kernel(
    const float* __restrict__ psum, const float* __restrict__ psq,
    const float* __restrict__ g, const float* __restrict__ be,
    float* __restrict__ scale, float* __restrict__ shift)
{
    const int c = threadIdx.x;
    float s = 0.0f, q = 0.0f;
    for (int b = 0; b < 512; ++b) { s += psum[b * HID + c]; q += psq[b * HID + c]; }
    const float inv_n = 1.0f / (float)N1T;
    const float mu = s * inv_n;
    const float var = fmaxf(q * inv_n - mu * mu, 0.0f);
    const float sc = g[c] * rsqrtf(var + BN_EPS);
    scale[c] = sc;
    shift[c] = be[c] - mu * sc;
}

// --------------------------------------------------------- final BN+ReLU
__global__ __launch_bounds__(256) void bn_apply_kernel(
    const float* __restrict__ y, const float* __restrict__ scale,
    const float* __restrict__ shift, float* __restrict__ out)
{
    const size_t i = (size_t)blockIdx.x * 256 + threadIdx.x;
    const int c4 = (int)(i & 63) * 4;
    float4 v = ((const float4*)y)[i];
    const float4 sc = *(const float4*)(scale + c4);
    const float4 sh = *(const float4*)(shift + c4);
    float4 o;
    o.x = fmaxf(fmaf(v.x, sc.x, sh.x), 0.0f);
    o.y = fmaxf(fmaf(v.y, sc.y, sh.y), 0.0f);
    o.z = fmaxf(fmaf(v.z, sc.z, sh.z), 0.0f);
    o.w = fmaxf(fmaf(v.w, sc.w, sh.w), 0.0f);
    ((float4*)out)[i] = o;
}

// -------------------------------------------------------------- launcher
extern "C" void kernel_launch(void* const* d_in, const int* in_sizes, int n_in,
                              void* d_out, int out_size, void* d_ws, size_t ws_size,
                              hipStream_t stream)
{
    const float* xyz1    = (const float*)d_in[0];
    const float* points1 = (const float*)d_in[1];
    const float* xyz2    = (const float*)d_in[2];
    const float* points2 = (const float*)d_in[3];
    const float* W1  = (const float*)d_in[6];
    const float* b1  = (const float*)d_in[7];
    const float* g1  = (const float*)d_in[8];
    const float* be1 = (const float*)d_in[9];
    const float* W2  = (const float*)d_in[10];
    const float* b2  = (const float*)d_in[11];
    const float* g2  = (const float*)d_in[12];
    const float* be2 = (const float*)d_in[13];
    float* out = (float*)d_out;

    char* ws = (char*)d_ws;
    // layout:
    //   [0, 100663296)           abuf bf16 [N1][768]; reused as y2 f32 [N1][256]
    //   [100663296, +33554432)   y1b bf16 [N1][256]
    //   [134217728, +16777216)   p2b bf16 [N2T][512]
    //   then w1t/w2t/idx/w/psum/psq/scales
    short* abuf = (short*)ws;
    short* y1b  = (short*)(ws + 100663296);
    short* p2b  = (short*)(ws + 134217728);
    size_t off  = 134217728 + 16777216;
    short* w1t    = (short*)(ws + off); off += (size_t)K1 * HID * 2;
    short* w2t    = (short*)(ws + off); off += (size_t)HID * HID * 2;
    int*   idx    = (int*)(ws + off);   off += (size_t)N1T * 3 * 4;
    float* w      = (float*)(ws + off); off += (size_t)N1T * 3 * 4;
    float* psum   = (float*)(ws + off); off += 512 * 256 * 4;
    float* psq    = (float*)(ws + off); off += 512 * 256 * 4;
    float* scale1 = (float*)(ws + off); off += 256 * 4;
    float* shift1 = (float*)(ws + off); off += 256 * 4;
    float* scale2 = (float*)(ws + off); off += 256 * 4;
    float* shift2 = (float*)(ws + off); off += 256 * 4;
    float* y2 = (float*)abuf;  // reuse: abuf dead after gemm1m

    cast_p1_kernel<<<N1T * C1 / 8 / 256, 256, 0, stream>>>(points1, abuf);
    cast_p2_kernel<<<N2T * C2 / 8 / 256, 256, 0, stream>>>(points2, p2b);
    transpose_w_kernel<<<K1 * HID / 256, 256, 0, stream>>>(W1, w1t, K1, HID);
    transpose_w_kernel<<<HID * HID / 256, 256, 0, stream>>>(W2, w2t, HID, HID);
    knn_kernel<<<1024, 256, 0, stream>>>(xyz1, xyz2, idx, w);
    interp_kernel<<<N1T, 128, 0, stream>>>(p2b, idx, w, abuf);
    gemm1m_kernel<<<dim3(HID / 128, N1T / 128), 256, 0, stream>>>(
        abuf, w1t, b1, y1b, psum, psq);
    bn_finalize_kernel<<<1, 256, 0, stream>>>(psum, psq, g1, be1, scale1, shift1);
    gemm2m_kernel<<<dim3(HID / 128, N1T / 128), 256, 0, stream>>>(
        y1b, scale1, shift1, w2t, b2, y2, psum, psq);
    bn_finalize_kernel<<<1, 256, 0, stream>>>(psum, psq, g2, be2, scale2, shift2);
    bn_apply_kernel<<<(N1T * HID / 4) / 256, 256, 0, stream>>>(y2, scale2, shift2, out);
}